// Round 3
// baseline (858.784 us; speedup 1.0000x reference)
//
#include <hip/hip_runtime.h>
#include <hip/hip_bf16.h>
#include <stdint.h>

typedef __bf16 bf16;
typedef __bf16 bf16x8 __attribute__((ext_vector_type(8)));
typedef __bf16 bf16x4 __attribute__((ext_vector_type(4)));
typedef float f32x4 __attribute__((ext_vector_type(4)));

static constexpr int BATCH = 4;
static constexpr int CH    = 512;
static constexpr int HH    = 64;
static constexpr int WW    = 80;
static constexpr int NSPAT = HH * WW;       // 5120
static constexpr int KCH   = 256;
static constexpr int VCH   = 512;
static constexpr int HPAD  = HH + 2;        // 66
static constexpr int WPAD  = WW + 2;        // 82
static constexpr int NPAD  = HPAD * WPAD;   // 5412
static constexpr float BN_EPS = 1e-5f;
static constexpr long  MNVN  = (long)VCH * NSPAT;  // 2621440

enum { MODE_LIN = 0, MODE_PAD = 1, MODE_CONV = 2, MODE_SIMF32 = 3 };
enum { EPI_KF = 0, EPI_S = 1, EPI_V1 = 2, EPI_V = 3, EPI_CTX = 4, EPI_RAW = 5, EPI_RAWT = 6 };

__device__ __forceinline__ void gll16(const void* g, void* l) {
  __builtin_amdgcn_global_load_lds((const __attribute__((address_space(1))) void*)g,
                                   (__attribute__((address_space(3))) void*)l,
                                   16, 0, 0);
}

// C[M,N] = A[M,K] * B[N,K]^T, bf16 in, fp32 acc. 128x128 tile, BK=32, 4 waves.
// Double-buffered LDS (min-2-phase: issue next stage before compute, 1 barrier/iter).
// LDS chunk swizzle: 16B chunk of (row r, chunk c) stored at slot r*4 + (c ^ ((r>>1)&3))
// -- realized by pre-swizzling the per-lane GLOBAL source (gll16 writes linearly) and
// reading fragments at the swizzled offset. Kills the 8-way ds_read_b128 bank conflict.
// EPI_S: blockIdx.x enumerates upper-triangle tiles (S symmetric); writes tile + mirror.
template<int MODE, int EPI, int KDIM, int KSPLIT = 1>
__global__ __launch_bounds__(256)
void k_gemm(const bf16* __restrict__ Ag, const void* __restrict__ Bg,
            void* __restrict__ Og, const float* __restrict__ ep0,
            const float* __restrict__ ep1,
            long Astr, long Bstr, long Ostr) {
  __shared__ bf16 As[2 * 128 * 32];
  __shared__ bf16 Bs[2 * 128 * 32];
  const int tid  = threadIdx.x;
  const int wave = tid >> 6;
  const int lane = tid & 63;
  const int zi = blockIdx.z;
  const int b  = (KSPLIT > 1) ? (zi / KSPLIT) : zi;
  const int sl = (KSPLIT > 1) ? (zi % KSPLIT) : 0;
  constexpr int KLEN = KDIM / KSPLIT;
  const int kb = sl * KLEN, kend = kb + KLEN;

  int m0, n0;
  if constexpr (EPI == EPI_S) {
    // upper-triangle tile enumeration, T = 40 row-tiles: C(i) = i*(81-i)/2
    const int t = blockIdx.x;
    int i = (int)((81.0f - sqrtf(6561.0f - 8.0f * (float)t)) * 0.5f);
    while ((i + 1) * (81 - (i + 1)) / 2 <= t) ++i;
    while (i * (81 - i) / 2 > t) --i;
    m0 = i * 128;
    n0 = (i + (t - i * (81 - i) / 2)) * 128;
  } else {
    n0 = blockIdx.x * 128;
    m0 = blockIdx.y * 128;
  }

  // staging: lane covers row = base + lane/4; fetches swizzled chunk cswz
  const int rloc = lane >> 2;
  const int cswz = (lane & 3) ^ ((lane >> 3) & 3);
  const int colo = cswz * 8;
  const int r0   = wave * 32 + rloc;
  const int r1   = r0 + 16;

  const bf16* Ab  = Ag + (long)b * Astr;
  const bf16* ag0 = Ab + (long)(m0 + r0) * KDIM + colo;
  const bf16* ag1 = Ab + (long)(m0 + r1) * KDIM + colo;
  bf16* al0 = As + wave * 1024;
  bf16* al1 = As + wave * 1024 + 512;
  bf16* bl0 = Bs + wave * 1024;
  bf16* bl1 = Bs + wave * 1024 + 512;

  const bf16*  BbB = (const bf16*)Bg + (long)b * Bstr;
  const float* Sg  = (const float*)Bg + (long)b * Bstr;
  const bf16* bg0 = nullptr;
  const bf16* bg1 = nullptr;
  int bsp0 = 0, bsp1 = 0;
  if constexpr (MODE == MODE_LIN) {
    bg0 = BbB + (long)(n0 + r0) * KDIM + colo;
    bg1 = BbB + (long)(n0 + r1) * KDIM + colo;
  } else if constexpr (MODE == MODE_PAD) {
    const int na = n0 + r0, nb = n0 + r1;
    bg0 = BbB + ((long)((na / WW + 1) * WPAD + (na % WW) + 1)) * CH + colo;
    bg1 = BbB + ((long)((nb / WW + 1) * WPAD + (nb % WW) + 1)) * CH + colo;
  } else if constexpr (MODE == MODE_CONV) {
    const int na = n0 + r0, nb = n0 + r1;
    bsp0 = (na / WW) * WPAD + (na % WW);
    bsp1 = (nb / WW) * WPAD + (nb % WW);
  }

  auto STAGE = [&](int k0, int buf) {
    const int o = buf << 12;  // 4096 elements per buffer
    gll16(ag0 + k0, al0 + o);
    gll16(ag1 + k0, al1 + o);
    if constexpr (MODE == MODE_LIN || MODE == MODE_PAD) {
      gll16(bg0 + k0, bl0 + o);
      gll16(bg1 + k0, bl1 + o);
    } else if constexpr (MODE == MODE_CONV) {
      const int tap    = k0 >> 9;
      const int within = k0 & 511;
      const int kh  = tap / 3;
      const int kw  = tap - kh * 3;
      const int off = kh * WPAD + kw;
      gll16(BbB + (long)(bsp0 + off) * CH + within + colo, bl0 + o);
      gll16(BbB + (long)(bsp1 + off) * CH + within + colo, bl1 + o);
    } else { // MODE_SIMF32: reg-stage fp32 -> bf16 LDS (swizzled ds_write)
      #pragma unroll
      for (int p = 0; p < 4; ++p) {
        const int idx = p * 256 + tid;
        const int rr  = idx >> 3;
        const int cg  = (idx & 7) * 4;
        const float4 f = *(const float4*)(Sg + (long)(n0 + rr) * NSPAT + k0 + cg);
        bf16x4 hq;
        hq[0] = (bf16)f.x; hq[1] = (bf16)f.y; hq[2] = (bf16)f.z; hq[3] = (bf16)f.w;
        const int chunk = cg >> 3;
        const int swc   = (((chunk ^ ((rr >> 1) & 3)) << 3) | (cg & 7));
        *(bf16x4*)(Bs + o + rr * 32 + swc) = hq;
      }
    }
  };

  f32x4 acc[4][4] = {};

  const int wm = wave >> 1, wn = wave & 1;
  const int fr  = lane & 15;
  const int qsw = (((lane >> 4) ^ ((fr >> 1) & 3)) << 3);  // swizzled chunk offset
  const bf16* ArF = As + (wm * 64 + fr) * 32 + qsw;
  const bf16* BrF = Bs + (wn * 64 + fr) * 32 + qsw;

  STAGE(kb, 0);
  __syncthreads();
  int cur = 0;
  for (int k0 = kb; k0 < kend; k0 += 32) {
    if (k0 + 32 < kend) STAGE(k0 + 32, cur ^ 1);
    const int off = cur << 12;
    bf16x8 af[4], bfv[4];
    #pragma unroll
    for (int i = 0; i < 4; ++i) af[i] = *(const bf16x8*)(ArF + off + i * 512);
    #pragma unroll
    for (int j = 0; j < 4; ++j) bfv[j] = *(const bf16x8*)(BrF + off + j * 512);
    #pragma unroll
    for (int i = 0; i < 4; ++i)
      #pragma unroll
      for (int j = 0; j < 4; ++j)
        acc[i][j] = __builtin_amdgcn_mfma_f32_16x16x32_bf16(af[i], bfv[j], acc[i][j], 0, 0, 0);
    __syncthreads();
    cur ^= 1;
  }

  const int row0 = m0 + wm * 64 + (lane >> 4) * 4;  // M index (+i*16+r)
  const int col0 = n0 + wn * 64 + (lane & 15);      // N index (+j*16)
  const long zo  = (long)zi * Ostr;

  if constexpr (EPI == EPI_KF || EPI == EPI_V1) {
    constexpr int LDO = (EPI == EPI_KF) ? KCH : VCH;
    bf16* op = (bf16*)Og + zo;
    #pragma unroll
    for (int i = 0; i < 4; ++i) {
      const int m = row0 + i * 16;
      float sc[4], bi[4];
      #pragma unroll
      for (int r = 0; r < 4; ++r) {
        if constexpr (EPI == EPI_KF) { sc[r] = ep0[m + r]; bi[r] = ep1[m + r]; }
        else                         { sc[r] = 1.0f;       bi[r] = ep0[m + r]; }
      }
      #pragma unroll
      for (int j = 0; j < 4; ++j) {
        const int n = col0 + j * 16;
        bf16x4 pk;
        #pragma unroll
        for (int r = 0; r < 4; ++r)
          pk[r] = (bf16)fmaxf(acc[i][j][r] * sc[r] + bi[r], 0.0f);
        *(bf16x4*)(op + (long)n * LDO + m) = pk;
      }
    }
  } else if constexpr (EPI == EPI_S) {
    float* op = (float*)Og + zo;
    #pragma unroll
    for (int i = 0; i < 4; ++i)
      #pragma unroll
      for (int j = 0; j < 4; ++j) {
        f32x4 sv = acc[i][j];
        sv[0] *= 0.0625f; sv[1] *= 0.0625f; sv[2] *= 0.0625f; sv[3] *= 0.0625f;
        // mirror tile [n][m]: contiguous over m -> 16B store
        *(f32x4*)(op + (long)(col0 + j * 16) * NSPAT + row0 + i * 16) = sv;
        // normal tile [m][n]
        #pragma unroll
        for (int r = 0; r < 4; ++r)
          op[(long)(row0 + i * 16 + r) * NSPAT + col0 + j * 16] = sv[r];
      }
  } else if constexpr (EPI == EPI_V) {
    bf16* op = (bf16*)Og + zo;   // v[m][n] row-major
    #pragma unroll
    for (int i = 0; i < 4; ++i)
      #pragma unroll
      for (int r = 0; r < 4; ++r) {
        const int m = row0 + i * 16 + r;
        const float bi = ep0[m];
        #pragma unroll
        for (int j = 0; j < 4; ++j)
          op[(long)m * NSPAT + col0 + j * 16] = (bf16)fmaxf(acc[i][j][r] + bi, 0.0f);
      }
  } else if constexpr (EPI == EPI_RAWT) {
    float* op = (float*)Og + zo;   // raw f32 [n][m], LDM = VCH, 16B stores
    #pragma unroll
    for (int i = 0; i < 4; ++i)
      #pragma unroll
      for (int j = 0; j < 4; ++j)
        *(f32x4*)(op + (long)(col0 + j * 16) * VCH + row0 + i * 16) = acc[i][j];
  } else { // EPI_CTX / EPI_RAW: raw f32 [m][n]
    float* op = (float*)Og + zo;
    #pragma unroll
    for (int i = 0; i < 4; ++i)
      #pragma unroll
      for (int r = 0; r < 4; ++r) {
        const long base = (long)(row0 + i * 16 + r) * NSPAT;
        #pragma unroll
        for (int j = 0; j < 4; ++j)
          op[base + col0 + j * 16] = acc[i][j][r];
      }
  }
}

template<int KS>
__global__ __launch_bounds__(256)
void k_red_ctx(const float* __restrict__ p, float* __restrict__ out) {
  const long idx = ((long)blockIdx.x * 256 + threadIdx.x) * 4;
  const int  b   = (int)(idx / MNVN);
  const long r   = idx - (long)b * MNVN;
  const float* pb = p + (long)b * KS * MNVN + r;
  float4 a = *(const float4*)pb;
  #pragma unroll
  for (int s = 1; s < KS; ++s) {
    const float4 q = *(const float4*)(pb + (long)s * MNVN);
    a.x += q.x; a.y += q.y; a.z += q.z; a.w += q.w;
  }
  *(float4*)(out + idx) = a;
}

template<int KS>
__global__ __launch_bounds__(256)
void k_red_v1(const float* __restrict__ p, const float* __restrict__ bias,
              bf16* __restrict__ out) {
  const long idx = ((long)blockIdx.x * 256 + threadIdx.x) * 4;
  const int  b   = (int)(idx / MNVN);
  const long r   = idx - (long)b * MNVN;
  const float* pb = p + (long)b * KS * MNVN + r;
  float4 a = *(const float4*)pb;
  #pragma unroll
  for (int s = 1; s < KS; ++s) {
    const float4 q = *(const float4*)(pb + (long)s * MNVN);
    a.x += q.x; a.y += q.y; a.z += q.z; a.w += q.w;
  }
  const int m = (int)(r & (VCH - 1));
  const float4 bb = *(const float4*)(bias + m);
  bf16x4 o;
  o[0] = (bf16)fmaxf(a.x + bb.x, 0.0f);
  o[1] = (bf16)fmaxf(a.y + bb.y, 0.0f);
  o[2] = (bf16)fmaxf(a.z + bb.z, 0.0f);
  o[3] = (bf16)fmaxf(a.w + bb.w, 0.0f);
  *(bf16x4*)(out + idx) = o;
}

// x [B][C][H][W] f32 -> xpadT [B][NPAD][C] bf16, borders zeroed here (no memset).
__global__ __launch_bounds__(256)
void k_xpad(const float* __restrict__ x, bf16* __restrict__ xp) {
  __shared__ float t[64 * 81];
  const int cb  = blockIdx.x;   // 8 blocks of 64 channels
  const int hp  = blockIdx.y;   // padded row 0..65
  const int b   = blockIdx.z;
  const int tid = threadIdx.x;
  const bool border = (hp == 0) || (hp == HPAD - 1);
  if (!border) {
    const float* xb = x + ((long)b * CH + cb * 64) * NSPAT + (hp - 1) * WW;
    for (int idx = tid; idx < 64 * 80; idx += 256) {
      const int cl = idx / 80;
      const int w  = idx - cl * 80;
      t[cl * 81 + w] = xb[(long)cl * NSPAT + w];
    }
    __syncthreads();
  }
  bf16* op = xp + ((long)b * NPAD + (long)hp * WPAD) * CH + cb * 64;
  for (int idx = tid; idx < WPAD * 64; idx += 256) {
    const int wp = idx >> 6;
    const int cl = idx & 63;
    float v = 0.0f;
    if (!border && wp >= 1 && wp <= WW) v = t[cl * 81 + (wp - 1)];
    op[(long)wp * CH + cl] = (bf16)v;
  }
}

__global__ void k_cvt(const float* __restrict__ in, bf16* __restrict__ out, int n) {
  const int i = blockIdx.x * 256 + threadIdx.x;
  if (i < n) out[i] = (bf16)in[i];
}

__global__ void k_cvt_wv1(const float* __restrict__ in, bf16* __restrict__ out) {
  const int o   = blockIdx.x * 256 + threadIdx.x;
  const int c   = o & 511;
  const int t2  = o >> 9;
  const int tap = t2 % 9;
  const int vc  = t2 / 9;
  out[o] = (bf16)in[((long)vc * 512 + c) * 9 + tap];
}

__global__ void k_bnp(const float* bk, const float* gamma, const float* beta,
                      const float* rmean, const float* rvar,
                      float* s, float* t) {
  const int k = threadIdx.x;
  const float sc = gamma[k] / sqrtf(rvar[k] + BN_EPS);
  s[k] = sc;
  t[k] = (bk[k] - rmean[k]) * sc + beta[k];
}

__global__ __launch_bounds__(256)
void k_softmax(float* __restrict__ S, bf16* __restrict__ outb) {
  const int tid = threadIdx.x;
  float* p = S + (long)blockIdx.x * NSPAT;
  float4 v[5];
  float mx = -3.0e38f;
  #pragma unroll
  for (int q = 0; q < 5; ++q) {
    v[q] = *(const float4*)(p + (q * 256 + tid) * 4);
    mx = fmaxf(mx, fmaxf(fmaxf(v[q].x, v[q].y), fmaxf(v[q].z, v[q].w)));
  }
  __shared__ float red[4];
  #pragma unroll
  for (int o = 32; o > 0; o >>= 1) mx = fmaxf(mx, __shfl_xor(mx, o));
  if ((tid & 63) == 0) red[tid >> 6] = mx;
  __syncthreads();
  mx = fmaxf(fmaxf(red[0], red[1]), fmaxf(red[2], red[3]));
  float sum = 0.0f;
  #pragma unroll
  for (int q = 0; q < 5; ++q) {
    v[q].x = __expf(v[q].x - mx);
    v[q].y = __expf(v[q].y - mx);
    v[q].z = __expf(v[q].z - mx);
    v[q].w = __expf(v[q].w - mx);
    sum += (v[q].x + v[q].y) + (v[q].z + v[q].w);
  }
  #pragma unroll
  for (int o = 32; o > 0; o >>= 1) sum += __shfl_xor(sum, o);
  __syncthreads();
  if ((tid & 63) == 0) red[tid >> 6] = sum;
  __syncthreads();
  sum = (red[0] + red[1]) + (red[2] + red[3]);
  const float inv = 1.0f / sum;
  bf16* ob = outb ? outb + (long)blockIdx.x * NSPAT : nullptr;
  #pragma unroll
  for (int q = 0; q < 5; ++q) {
    float4 o4;
    o4.x = v[q].x * inv; o4.y = v[q].y * inv;
    o4.z = v[q].z * inv; o4.w = v[q].w * inv;
    *(float4*)(p + (q * 256 + tid) * 4) = o4;
    if (outb) {
      bf16x4 hb;
      hb[0] = (bf16)o4.x; hb[1] = (bf16)o4.y; hb[2] = (bf16)o4.z; hb[3] = (bf16)o4.w;
      *(bf16x4*)(ob + (q * 256 + tid) * 4) = hb;
    }
  }
}

extern "C" void kernel_launch(void* const* d_in, const int* in_sizes, int n_in,
                              void* d_out, int out_size, void* d_ws, size_t ws_size,
                              hipStream_t stream) {
  const float* x     = (const float*)d_in[0];
  const float* wk    = (const float*)d_in[1];
  const float* bk    = (const float*)d_in[2];
  const float* gamma = (const float*)d_in[3];
  const float* beta  = (const float*)d_in[4];
  const float* rmean = (const float*)d_in[5];
  const float* rvar  = (const float*)d_in[6];
  const float* wv1   = (const float*)d_in[7];
  const float* bv1   = (const float*)d_in[8];
  const float* wv2   = (const float*)d_in[9];
  const float* bv2   = (const float*)d_in[10];

  float* ctx = (float*)d_out;                    // [B][VC][N]
  float* Sb  = ctx + (long)BATCH * VCH * NSPAT;  // [B][N][N]

  char* w = (char*)d_ws;
  auto alloc = [&](size_t bytes) {
    char* r = w;
    w += (bytes + 255) & ~(size_t)255;
    return r;
  };
  bf16*  xpadT = (bf16*)alloc((size_t)BATCH * NPAD * CH * 2);
  bf16*  kfT   = (bf16*)alloc((size_t)BATCH * NSPAT * KCH * 2);
  bf16*  v1T   = (bf16*)alloc((size_t)BATCH * NSPAT * VCH * 2);
  bf16*  vB    = (bf16*)alloc((size_t)BATCH * VCH * NSPAT * 2);
  bf16*  wkb   = (bf16*)alloc((size_t)KCH * CH * 2);
  bf16*  wv1b  = (bf16*)alloc((size_t)VCH * CH * 9 * 2);
  bf16*  wv2b  = (bf16*)alloc((size_t)VCH * VCH * 2);
  float* bnS   = (float*)alloc(KCH * 4);
  float* bnT   = (float*)alloc(KCH * 4);
  const size_t used = (size_t)(w - (char*)d_ws);
  if (ws_size < used) return;
  const size_t avail    = ws_size - used;
  const size_t simbytes = (size_t)BATCH * NSPAT * NSPAT * 2;  // 209.7 MB
  const size_t part2    = (size_t)2 * BATCH * MNVN * 4;       //  83.9 MB
  int    ks   = 1;
  float* part = nullptr;
  bf16*  simb = nullptr;
  if (avail >= part2 + simbytes) { ks = 2; part = (float*)alloc(part2); simb = (bf16*)alloc(simbytes); }
  else if (avail >= part2)       { ks = 2; part = (float*)alloc(part2); }
  else if (avail >= simbytes)    { simb = (bf16*)alloc(simbytes); }

  k_xpad<<<dim3(8, HPAD, BATCH), 256, 0, stream>>>(x, xpadT);
  k_cvt<<<(KCH * CH) / 256, 256, 0, stream>>>(wk, wkb, KCH * CH);
  k_cvt_wv1<<<(VCH * CH * 9) / 256, 256, 0, stream>>>(wv1, wv1b);
  k_cvt<<<(VCH * VCH) / 256, 256, 0, stream>>>(wv2, wv2b, VCH * VCH);
  k_bnp<<<1, KCH, 0, stream>>>(bk, gamma, beta, rmean, rvar, bnS, bnT);

  const int redBlocks = (int)((long)BATCH * MNVN / 4 / 256);  // 10240

  // G1: kfT[b][n][kc] = relu(bn(wk . x))
  k_gemm<MODE_PAD, EPI_KF, CH><<<dim3(NSPAT / 128, KCH / 128, BATCH), 256, 0, stream>>>(
      wkb, xpadT, kfT, bnS, bnT, 0, (long)NPAD * CH, (long)NSPAT * KCH);
  // G2: S[b][n][m] = kf_n . kf_m / 16 (symmetric: 820 triangle tiles, dual write)
  k_gemm<MODE_LIN, EPI_S, KCH><<<dim3(820, 1, BATCH), 256, 0, stream>>>(
      kfT, kfT, Sb, nullptr, nullptr, (long)NSPAT * KCH, (long)NSPAT * KCH, (long)NSPAT * NSPAT);
  // G3: v1T[b][n][vc] = relu(conv3x3(x))
  if (ks == 2) {
    k_gemm<MODE_CONV, EPI_RAWT, CH * 9, 2><<<dim3(NSPAT / 128, VCH / 128, BATCH * 2), 256, 0, stream>>>(
        wv1b, xpadT, part, nullptr, nullptr, 0, (long)NPAD * CH, MNVN);
    k_red_v1<2><<<redBlocks, 256, 0, stream>>>(part, bv1, v1T);
  } else {
    k_gemm<MODE_CONV, EPI_V1, CH * 9><<<dim3(NSPAT / 128, VCH / 128, BATCH), 256, 0, stream>>>(
        wv1b, xpadT, v1T, bv1, nullptr, 0, (long)NPAD * CH, (long)NSPAT * VCH);
  }
  // G4: v[b][vc][n] = relu(wv2 . v1)
  k_gemm<MODE_LIN, EPI_V, VCH><<<dim3(NSPAT / 128, VCH / 128, BATCH), 256, 0, stream>>>(
      wv2b, v1T, vB, bv2, nullptr, 0, (long)NSPAT * VCH, (long)VCH * NSPAT);
  // softmax rows of S (in place, fp32) + bf16 copy for G5
  k_softmax<<<BATCH * NSPAT, 256, 0, stream>>>(Sb, simb);
  // G5: context[b][vc][n] = sum_m v[vc][m] * sim[n][m]
  if (simb) {
    if (ks == 2) {
      k_gemm<MODE_LIN, EPI_RAW, NSPAT, 2><<<dim3(NSPAT / 128, VCH / 128, BATCH * 2), 256, 0, stream>>>(
          vB, simb, part, nullptr, nullptr, (long)VCH * NSPAT, (long)NSPAT * NSPAT, MNVN);
      k_red_ctx<2><<<redBlocks, 256, 0, stream>>>(part, ctx);
    } else {
      k_gemm<MODE_LIN, EPI_CTX, NSPAT><<<dim3(NSPAT / 128, VCH / 128, BATCH), 256, 0, stream>>>(
          vB, simb, ctx, nullptr, nullptr, (long)VCH * NSPAT, (long)NSPAT * NSPAT, (long)VCH * NSPAT);
    }
  } else {
    if (ks == 2) {
      k_gemm<MODE_SIMF32, EPI_RAW, NSPAT, 2><<<dim3(NSPAT / 128, VCH / 128, BATCH * 2), 256, 0, stream>>>(
          vB, Sb, part, nullptr, nullptr, (long)VCH * NSPAT, (long)NSPAT * NSPAT, MNVN);
      k_red_ctx<2><<<redBlocks, 256, 0, stream>>>(part, ctx);
    } else {
      k_gemm<MODE_SIMF32, EPI_CTX, NSPAT><<<dim3(NSPAT / 128, VCH / 128, BATCH), 256, 0, stream>>>(
          vB, Sb, ctx, nullptr, nullptr, (long)VCH * NSPAT, (long)NSPAT * NSPAT, (long)VCH * NSPAT);
    }
  }
}

// Round 4
// 677.368 us; speedup vs baseline: 1.2678x; 1.2678x over previous
//
#include <hip/hip_runtime.h>
#include <hip/hip_bf16.h>
#include <stdint.h>

typedef __bf16 bf16;
typedef __bf16 bf16x8 __attribute__((ext_vector_type(8)));
typedef __bf16 bf16x4 __attribute__((ext_vector_type(4)));
typedef float f32x4 __attribute__((ext_vector_type(4)));

static constexpr int BATCH = 4;
static constexpr int CH    = 512;
static constexpr int HH    = 64;
static constexpr int WW    = 80;
static constexpr int NSPAT = HH * WW;       // 5120
static constexpr int KCH   = 256;
static constexpr int VCH   = 512;
static constexpr int HPAD  = HH + 2;        // 66
static constexpr int WPAD  = WW + 2;        // 82
static constexpr int NPAD  = HPAD * WPAD;   // 5412
static constexpr float BN_EPS = 1e-5f;

enum { MODE_LIN = 0, MODE_PAD = 1, MODE_CONV = 2, MODE_SIMF32 = 3 };
enum { EPI_KF = 0, EPI_SBF = 1, EPI_SF32 = 2, EPI_V1 = 3, EPI_V = 4, EPI_CTX = 5 };

__device__ __forceinline__ void gll16(const void* g, void* l) {
  __builtin_amdgcn_global_load_lds((const __attribute__((address_space(1))) void*)g,
                                   (__attribute__((address_space(3))) void*)l,
                                   16, 0, 0);
}

// C[M,N] = A[M,K] * B[N,K]^T, bf16 in, fp32 acc. 128x128 tile, BK=32, 4 waves.
// 2-phase double-buffered LDS; chunk-swizzled LDS layout via pre-swizzled global
// source (gll16 dest is linear) + matching swizzled ds_read offsets.
// Grid: blockIdx.x = flattened (n-tile, m-tile) with XCD-aware remap:
//   d = (x%8) + 8*y + 8*NY*(x/8)  -- the NY m-tiles sharing a B n-stripe get
//   dispatch ids congruent mod 8 -> same XCD L2. Requires NX%8==0 (NX=40 ok).
// EPI_SBF/EPI_SF32 write the tile TRANSPOSED (S is symmetric) -> vector stores.
template<int MODE, int EPI, int KDIM, int NY>
__global__ __launch_bounds__(256)
void k_gemm(const bf16* __restrict__ Ag, const void* __restrict__ Bg,
            void* __restrict__ Og, const float* __restrict__ ep0,
            const float* __restrict__ ep1,
            long Astr, long Bstr, long Ostr) {
  __shared__ bf16 As[2 * 128 * 32];
  __shared__ bf16 Bs[2 * 128 * 32];
  const int tid  = threadIdx.x;
  const int wave = tid >> 6;
  const int lane = tid & 63;
  const int b    = blockIdx.z;

  const int d  = blockIdx.x;
  const int xl = d & 7;
  const int y  = (d >> 3) % NY;
  const int xh = d / (8 * NY);
  const int n0 = (xh * 8 + xl) * 128;
  const int m0 = y * 128;

  // staging: lane covers row = base + lane/4, fetches swizzled global chunk
  const int rloc = lane >> 2;
  const int cswz = (lane & 3) ^ ((lane >> 3) & 3);
  const int colo = cswz * 8;
  const int r0   = wave * 32 + rloc;
  const int r1   = r0 + 16;

  const bf16* Ab  = Ag + (long)b * Astr;
  const bf16* ag0 = Ab + (long)(m0 + r0) * KDIM + colo;
  const bf16* ag1 = Ab + (long)(m0 + r1) * KDIM + colo;
  bf16* al0 = As + wave * 1024;
  bf16* al1 = As + wave * 1024 + 512;
  bf16* bl0 = Bs + wave * 1024;
  bf16* bl1 = Bs + wave * 1024 + 512;

  const bf16*  BbB = (const bf16*)Bg + (long)b * Bstr;
  const float* Sg  = (const float*)Bg + (long)b * Bstr;
  const bf16* bg0 = nullptr;
  const bf16* bg1 = nullptr;
  int bsp0 = 0, bsp1 = 0;
  if constexpr (MODE == MODE_LIN) {
    bg0 = BbB + (long)(n0 + r0) * KDIM + colo;
    bg1 = BbB + (long)(n0 + r1) * KDIM + colo;
  } else if constexpr (MODE == MODE_PAD) {
    const int na = n0 + r0, nb = n0 + r1;
    bg0 = BbB + ((long)((na / WW + 1) * WPAD + (na % WW) + 1)) * CH + colo;
    bg1 = BbB + ((long)((nb / WW + 1) * WPAD + (nb % WW) + 1)) * CH + colo;
  } else if constexpr (MODE == MODE_CONV) {
    const int na = n0 + r0, nb = n0 + r1;
    bsp0 = (na / WW) * WPAD + (na % WW);
    bsp1 = (nb / WW) * WPAD + (nb % WW);
  }

  auto STAGE = [&](int k0, int buf) {
    const int o = buf << 12;
    gll16(ag0 + k0, al0 + o);
    gll16(ag1 + k0, al1 + o);
    if constexpr (MODE == MODE_LIN || MODE == MODE_PAD) {
      gll16(bg0 + k0, bl0 + o);
      gll16(bg1 + k0, bl1 + o);
    } else if constexpr (MODE == MODE_CONV) {
      const int tap    = k0 >> 9;
      const int within = k0 & 511;
      const int kh  = tap / 3;
      const int kw  = tap - kh * 3;
      const int off = kh * WPAD + kw;
      gll16(BbB + (long)(bsp0 + off) * CH + within + colo, bl0 + o);
      gll16(BbB + (long)(bsp1 + off) * CH + within + colo, bl1 + o);
    } else { // MODE_SIMF32: reg-stage fp32 -> bf16 LDS (swizzled ds_write)
      #pragma unroll
      for (int p = 0; p < 4; ++p) {
        const int idx = p * 256 + tid;
        const int rr  = idx >> 3;
        const int cg  = (idx & 7) * 4;
        const float4 f = *(const float4*)(Sg + (long)(n0 + rr) * NSPAT + k0 + cg);
        bf16x4 hq;
        hq[0] = (bf16)f.x; hq[1] = (bf16)f.y; hq[2] = (bf16)f.z; hq[3] = (bf16)f.w;
        const int chunk = cg >> 3;
        const int swc   = (((chunk ^ ((rr >> 1) & 3)) << 3) | (cg & 7));
        *(bf16x4*)(Bs + o + rr * 32 + swc) = hq;
      }
    }
  };

  f32x4 acc[4][4] = {};

  const int wm = wave >> 1, wn = wave & 1;
  const int fr  = lane & 15;
  const int qsw = (((lane >> 4) ^ ((fr >> 1) & 3)) << 3);
  const bf16* ArF = As + (wm * 64 + fr) * 32 + qsw;
  const bf16* BrF = Bs + (wn * 64 + fr) * 32 + qsw;

  STAGE(0, 0);
  __syncthreads();
  int cur = 0;
  for (int k0 = 0; k0 < KDIM; k0 += 32) {
    if (k0 + 32 < KDIM) STAGE(k0 + 32, cur ^ 1);
    const int off = cur << 12;
    bf16x8 af[4], bfv[4];
    #pragma unroll
    for (int i = 0; i < 4; ++i) af[i] = *(const bf16x8*)(ArF + off + i * 512);
    #pragma unroll
    for (int j = 0; j < 4; ++j) bfv[j] = *(const bf16x8*)(BrF + off + j * 512);
    #pragma unroll
    for (int i = 0; i < 4; ++i)
      #pragma unroll
      for (int j = 0; j < 4; ++j)
        acc[i][j] = __builtin_amdgcn_mfma_f32_16x16x32_bf16(af[i], bfv[j], acc[i][j], 0, 0, 0);
    __syncthreads();
    cur ^= 1;
  }

  const int row0 = m0 + wm * 64 + (lane >> 4) * 4;  // M index (+i*16+r)
  const int col0 = n0 + wn * 64 + (lane & 15);      // N index (+j*16)
  const long zo  = (long)b * Ostr;

  if constexpr (EPI == EPI_KF || EPI == EPI_V1) {
    constexpr int LDO = (EPI == EPI_KF) ? KCH : VCH;
    bf16* op = (bf16*)Og + zo;
    #pragma unroll
    for (int i = 0; i < 4; ++i) {
      const int m = row0 + i * 16;
      float sc[4], bi[4];
      #pragma unroll
      for (int r = 0; r < 4; ++r) {
        if constexpr (EPI == EPI_KF) { sc[r] = ep0[m + r]; bi[r] = ep1[m + r]; }
        else                         { sc[r] = 1.0f;       bi[r] = ep0[m + r]; }
      }
      #pragma unroll
      for (int j = 0; j < 4; ++j) {
        const int n = col0 + j * 16;
        bf16x4 pk;
        #pragma unroll
        for (int r = 0; r < 4; ++r)
          pk[r] = (bf16)fmaxf(acc[i][j][r] * sc[r] + bi[r], 0.0f);
        *(bf16x4*)(op + (long)n * LDO + m) = pk;
      }
    }
  } else if constexpr (EPI == EPI_SBF) {
    // bf16 scores * KC^-0.5, transposed write (S symmetric) -> 8B stores
    bf16* op = (bf16*)Og + zo;
    #pragma unroll
    for (int i = 0; i < 4; ++i)
      #pragma unroll
      for (int j = 0; j < 4; ++j) {
        bf16x4 pk;
        #pragma unroll
        for (int r = 0; r < 4; ++r) pk[r] = (bf16)(acc[i][j][r] * 0.0625f);
        *(bf16x4*)(op + (long)(col0 + j * 16) * NSPAT + row0 + i * 16) = pk;
      }
  } else if constexpr (EPI == EPI_SF32) {
    // f32 scores, transposed write (S symmetric) -> 16B stores
    float* op = (float*)Og + zo;
    #pragma unroll
    for (int i = 0; i < 4; ++i)
      #pragma unroll
      for (int j = 0; j < 4; ++j) {
        f32x4 sv = acc[i][j];
        sv[0] *= 0.0625f; sv[1] *= 0.0625f; sv[2] *= 0.0625f; sv[3] *= 0.0625f;
        *(f32x4*)(op + (long)(col0 + j * 16) * NSPAT + row0 + i * 16) = sv;
      }
  } else if constexpr (EPI == EPI_V) {
    bf16* op = (bf16*)Og + zo;   // v[m][n] row-major
    #pragma unroll
    for (int i = 0; i < 4; ++i)
      #pragma unroll
      for (int r = 0; r < 4; ++r) {
        const int m = row0 + i * 16 + r;
        const float bi = ep0[m];
        #pragma unroll
        for (int j = 0; j < 4; ++j)
          op[(long)m * NSPAT + col0 + j * 16] = (bf16)fmaxf(acc[i][j][r] + bi, 0.0f);
      }
  } else { // EPI_CTX: f32 [m][n]
    float* op = (float*)Og + zo;
    #pragma unroll
    for (int i = 0; i < 4; ++i)
      #pragma unroll
      for (int r = 0; r < 4; ++r) {
        const long base = (long)(row0 + i * 16 + r) * NSPAT;
        #pragma unroll
        for (int j = 0; j < 4; ++j)
          op[base + col0 + j * 16] = acc[i][j][r];
      }
  }
}

// x [B][C][H][W] f32 -> xpadT [B][NPAD][C] bf16, borders zeroed here.
__global__ __launch_bounds__(256)
void k_xpad(const float* __restrict__ x, bf16* __restrict__ xp) {
  __shared__ float t[64 * 81];
  const int cb  = blockIdx.x;
  const int hp  = blockIdx.y;
  const int b   = blockIdx.z;
  const int tid = threadIdx.x;
  const bool border = (hp == 0) || (hp == HPAD - 1);
  if (!border) {
    const float* xb = x + ((long)b * CH + cb * 64) * NSPAT + (hp - 1) * WW;
    for (int idx = tid; idx < 64 * 80; idx += 256) {
      const int cl = idx / 80;
      const int w  = idx - cl * 80;
      t[cl * 81 + w] = xb[(long)cl * NSPAT + w];
    }
    __syncthreads();
  }
  bf16* op = xp + ((long)b * NPAD + (long)hp * WPAD) * CH + cb * 64;
  for (int idx = tid; idx < WPAD * 64; idx += 256) {
    const int wp = idx >> 6;
    const int cl = idx & 63;
    float v = 0.0f;
    if (!border && wp >= 1 && wp <= WW) v = t[cl * 81 + (wp - 1)];
    op[(long)wp * CH + cl] = (bf16)v;
  }
}

__global__ void k_cvt(const float* __restrict__ in, bf16* __restrict__ out, int n) {
  const int i = blockIdx.x * 256 + threadIdx.x;
  if (i < n) out[i] = (bf16)in[i];
}

__global__ void k_cvt_wv1(const float* __restrict__ in, bf16* __restrict__ out) {
  const int o   = blockIdx.x * 256 + threadIdx.x;
  const int c   = o & 511;
  const int t2  = o >> 9;
  const int tap = t2 % 9;
  const int vc  = t2 / 9;
  out[o] = (bf16)in[((long)vc * 512 + c) * 9 + tap];
}

__global__ void k_bnp(const float* bk, const float* gamma, const float* beta,
                      const float* rmean, const float* rvar,
                      float* s, float* t) {
  const int k = threadIdx.x;
  const float sc = gamma[k] / sqrtf(rvar[k] + BN_EPS);
  s[k] = sc;
  t[k] = (bk[k] - rmean[k]) * sc + beta[k];
}

// main path: read bf16 scores, f32 softmax, write f32 sim (d_out) + bf16 in-place
__global__ __launch_bounds__(256)
void k_softmax_bf(bf16* __restrict__ Sb16, float* __restrict__ Sout) {
  const int tid = threadIdx.x;
  bf16*  p  = Sb16 + (long)blockIdx.x * NSPAT;
  float* po = Sout + (long)blockIdx.x * NSPAT;
  float v[20];
  float mx = -3.0e38f;
  #pragma unroll
  for (int q = 0; q < 5; ++q) {
    const bf16x4 h = *(const bf16x4*)(p + (q * 256 + tid) * 4);
    #pragma unroll
    for (int r = 0; r < 4; ++r) {
      v[q * 4 + r] = (float)h[r];
      mx = fmaxf(mx, v[q * 4 + r]);
    }
  }
  __shared__ float red[4];
  #pragma unroll
  for (int o = 32; o > 0; o >>= 1) mx = fmaxf(mx, __shfl_xor(mx, o));
  if ((tid & 63) == 0) red[tid >> 6] = mx;
  __syncthreads();
  mx = fmaxf(fmaxf(red[0], red[1]), fmaxf(red[2], red[3]));
  float sum = 0.0f;
  #pragma unroll
  for (int e = 0; e < 20; ++e) { v[e] = __expf(v[e] - mx); sum += v[e]; }
  #pragma unroll
  for (int o = 32; o > 0; o >>= 1) sum += __shfl_xor(sum, o);
  __syncthreads();
  if ((tid & 63) == 0) red[tid >> 6] = sum;
  __syncthreads();
  sum = (red[0] + red[1]) + (red[2] + red[3]);
  const float inv = 1.0f / sum;
  #pragma unroll
  for (int q = 0; q < 5; ++q) {
    float4 o4;
    o4.x = v[q * 4 + 0] * inv; o4.y = v[q * 4 + 1] * inv;
    o4.z = v[q * 4 + 2] * inv; o4.w = v[q * 4 + 3] * inv;
    *(float4*)(po + (q * 256 + tid) * 4) = o4;
    bf16x4 hb;
    hb[0] = (bf16)o4.x; hb[1] = (bf16)o4.y; hb[2] = (bf16)o4.z; hb[3] = (bf16)o4.w;
    *(bf16x4*)(p + (q * 256 + tid) * 4) = hb;
  }
}

// fallback: f32 softmax in place
__global__ __launch_bounds__(256)
void k_softmax(float* __restrict__ S) {
  const int tid = threadIdx.x;
  float* p = S + (long)blockIdx.x * NSPAT;
  float4 v[5];
  float mx = -3.0e38f;
  #pragma unroll
  for (int q = 0; q < 5; ++q) {
    v[q] = *(const float4*)(p + (q * 256 + tid) * 4);
    mx = fmaxf(mx, fmaxf(fmaxf(v[q].x, v[q].y), fmaxf(v[q].z, v[q].w)));
  }
  __shared__ float red[4];
  #pragma unroll
  for (int o = 32; o > 0; o >>= 1) mx = fmaxf(mx, __shfl_xor(mx, o));
  if ((tid & 63) == 0) red[tid >> 6] = mx;
  __syncthreads();
  mx = fmaxf(fmaxf(red[0], red[1]), fmaxf(red[2], red[3]));
  float sum = 0.0f;
  #pragma unroll
  for (int q = 0; q < 5; ++q) {
    v[q].x = __expf(v[q].x - mx);
    v[q].y = __expf(v[q].y - mx);
    v[q].z = __expf(v[q].z - mx);
    v[q].w = __expf(v[q].w - mx);
    sum += (v[q].x + v[q].y) + (v[q].z + v[q].w);
  }
  #pragma unroll
  for (int o = 32; o > 0; o >>= 1) sum += __shfl_xor(sum, o);
  __syncthreads();
  if ((tid & 63) == 0) red[tid >> 6] = sum;
  __syncthreads();
  sum = (red[0] + red[1]) + (red[2] + red[3]);
  const float inv = 1.0f / sum;
  #pragma unroll
  for (int q = 0; q < 5; ++q) {
    float4 o4;
    o4.x = v[q].x * inv; o4.y = v[q].y * inv;
    o4.z = v[q].z * inv; o4.w = v[q].w * inv;
    *(float4*)(p + (q * 256 + tid) * 4) = o4;
  }
}

extern "C" void kernel_launch(void* const* d_in, const int* in_sizes, int n_in,
                              void* d_out, int out_size, void* d_ws, size_t ws_size,
                              hipStream_t stream) {
  const float* x     = (const float*)d_in[0];
  const float* wk    = (const float*)d_in[1];
  const float* bk    = (const float*)d_in[2];
  const float* gamma = (const float*)d_in[3];
  const float* beta  = (const float*)d_in[4];
  const float* rmean = (const float*)d_in[5];
  const float* rvar  = (const float*)d_in[6];
  const float* wv1   = (const float*)d_in[7];
  const float* bv1   = (const float*)d_in[8];
  const float* wv2   = (const float*)d_in[9];
  const float* bv2   = (const float*)d_in[10];

  float* ctx = (float*)d_out;                    // [B][VC][N]
  float* Sb  = ctx + (long)BATCH * VCH * NSPAT;  // [B][N][N] f32 sim output

  char* w = (char*)d_ws;
  auto alloc = [&](size_t bytes) {
    char* r = w;
    w += (bytes + 255) & ~(size_t)255;
    return r;
  };
  bf16*  xpadT = (bf16*)alloc((size_t)BATCH * NPAD * CH * 2);
  bf16*  kfT   = (bf16*)alloc((size_t)BATCH * NSPAT * KCH * 2);
  bf16*  v1T   = (bf16*)alloc((size_t)BATCH * NSPAT * VCH * 2);
  bf16*  vB    = (bf16*)alloc((size_t)BATCH * VCH * NSPAT * 2);
  bf16*  wkb   = (bf16*)alloc((size_t)KCH * CH * 2);
  bf16*  wv1b  = (bf16*)alloc((size_t)VCH * CH * 9 * 2);
  bf16*  wv2b  = (bf16*)alloc((size_t)VCH * VCH * 2);
  float* bnS   = (float*)alloc(KCH * 4);
  float* bnT   = (float*)alloc(KCH * 4);
  const size_t used = (size_t)(w - (char*)d_ws);
  if (ws_size < used) return;
  const size_t simbytes = (size_t)BATCH * NSPAT * NSPAT * 2;  // 209.7 MB
  bf16* simb = (ws_size - used >= simbytes) ? (bf16*)alloc(simbytes) : nullptr;

  k_xpad<<<dim3(8, HPAD, BATCH), 256, 0, stream>>>(x, xpadT);
  k_cvt<<<(KCH * CH) / 256, 256, 0, stream>>>(wk, wkb, KCH * CH);
  k_cvt_wv1<<<(VCH * CH * 9) / 256, 256, 0, stream>>>(wv1, wv1b);
  k_cvt<<<(VCH * VCH) / 256, 256, 0, stream>>>(wv2, wv2b, VCH * VCH);
  k_bnp<<<1, KCH, 0, stream>>>(bk, gamma, beta, rmean, rvar, bnS, bnT);

  // G1: kfT[b][n][kc] = relu(bn(wk . x))
  k_gemm<MODE_PAD, EPI_KF, CH, 2><<<dim3(40 * 2, 1, BATCH), 256, 0, stream>>>(
      wkb, xpadT, kfT, bnS, bnT, 0, (long)NPAD * CH, (long)NSPAT * KCH);
  // G3: v1T[b][n][vc] = relu(conv3x3(x))
  k_gemm<MODE_CONV, EPI_V1, CH * 9, 4><<<dim3(40 * 4, 1, BATCH), 256, 0, stream>>>(
      wv1b, xpadT, v1T, bv1, nullptr, 0, (long)NPAD * CH, (long)NSPAT * VCH);
  // G4: v[b][vc][n] = relu(wv2 . v1)
  k_gemm<MODE_LIN, EPI_V, VCH, 4><<<dim3(40 * 4, 1, BATCH), 256, 0, stream>>>(
      wv2b, v1T, vB, bv2, nullptr, 0, (long)NSPAT * VCH, (long)VCH * NSPAT);

  if (simb) {
    // G2: scores bf16 -> simb; softmax -> f32 sim (d_out) + bf16 (simb, in place)
    k_gemm<MODE_LIN, EPI_SBF, KCH, 40><<<dim3(40 * 40, 1, BATCH), 256, 0, stream>>>(
        kfT, kfT, simb, nullptr, nullptr, (long)NSPAT * KCH, (long)NSPAT * KCH, (long)NSPAT * NSPAT);
    k_softmax_bf<<<BATCH * NSPAT, 256, 0, stream>>>(simb, Sb);
    // G5: context = v . sim^T (bf16 sim)
    k_gemm<MODE_LIN, EPI_CTX, NSPAT, 4><<<dim3(40 * 4, 1, BATCH), 256, 0, stream>>>(
        vB, simb, ctx, nullptr, nullptr, (long)VCH * NSPAT, (long)NSPAT * NSPAT, (long)VCH * NSPAT);
  } else {
    // fallback: f32 scores in d_out sim region, in-place softmax, f32-staged G5
    k_gemm<MODE_LIN, EPI_SF32, KCH, 40><<<dim3(40 * 40, 1, BATCH), 256, 0, stream>>>(
        kfT, kfT, Sb, nullptr, nullptr, (long)NSPAT * KCH, (long)NSPAT * KCH, (long)NSPAT * NSPAT);
    k_softmax<<<BATCH * NSPAT, 256, 0, stream>>>(Sb);
    k_gemm<MODE_SIMF32, EPI_CTX, NSPAT, 4><<<dim3(40 * 4, 1, BATCH), 256, 0, stream>>>(
        vB, Sb, ctx, nullptr, nullptr, (long)VCH * NSPAT, (long)NSPAT * NSPAT, (long)VCH * NSPAT);
  }
}

// Round 5
// 669.140 us; speedup vs baseline: 1.2834x; 1.0123x over previous
//
#include <hip/hip_runtime.h>
#include <hip/hip_bf16.h>
#include <stdint.h>

typedef __bf16 bf16;
typedef __bf16 bf16x8 __attribute__((ext_vector_type(8)));
typedef __bf16 bf16x4 __attribute__((ext_vector_type(4)));
typedef float f32x4 __attribute__((ext_vector_type(4)));

static constexpr int BATCH = 4;
static constexpr int CH    = 512;
static constexpr int HH    = 64;
static constexpr int WW    = 80;
static constexpr int NSPAT = HH * WW;       // 5120
static constexpr int KCH   = 256;
static constexpr int VCH   = 512;
static constexpr int HPAD  = HH + 2;        // 66
static constexpr int WPAD  = WW + 2;        // 82
static constexpr int NPAD  = HPAD * WPAD;   // 5412
static constexpr float BN_EPS = 1e-5f;

enum { MODE_LIN = 0, MODE_PAD = 1, MODE_CONV = 2, MODE_SIMF32 = 3 };
enum { EPI_KF = 0, EPI_SBF = 1, EPI_SF32 = 2, EPI_V1 = 3, EPI_V = 4, EPI_CTX = 5 };

__device__ __forceinline__ void gll16(const void* g, void* l) {
  __builtin_amdgcn_global_load_lds((const __attribute__((address_space(1))) void*)g,
                                   (__attribute__((address_space(3))) void*)l,
                                   16, 0, 0);
}

// ---------------------------------------------------------------------------
// k_gemm2: deep-pipelined GEMM. C[M,N] = A[M,K]*B[N,K]^T, bf16 in, f32 acc.
// BM=256, BN=128, BK=64, 512 threads (8 waves, 2M x 4N), per-wave out 128x32.
// LDS: 3-buffer ring (A 3x16K + B 3x8K elems = 144 KiB). Iteration t consumes
// buf[t%3] and stages K-tile t+2 into buf[(t+2)%3] (free since t-1 finished).
// Boundary: s_waitcnt vmcnt(6) (tile t+2's 6 loads stay in flight ACROSS the
// barrier; tile t+1 was issued a full iteration earlier) + raw s_barrier.
// T2 swizzle: LDS slot (row,chunk c) holds global chunk c^(row&7); realized by
// pre-swizzled global source (gll16 dest must stay linear) + swizzled ds_read.
// T5 setprio(1) around each 16-MFMA cluster.
template<int MODE, int EPI, int KDIM, int REMAP>
__global__ __launch_bounds__(512, 2)
void k_gemm2(const bf16* __restrict__ Ag, const void* __restrict__ Bg,
             void* __restrict__ Og, const float* __restrict__ ep0,
             long Astr, long Bstr, long Ostr, int ntn) {
  __shared__ bf16 As[3 * 16384];
  __shared__ bf16 Bs[3 * 8192];
  constexpr int NT = KDIM / 64;
  const int tid  = threadIdx.x;
  const int wave = tid >> 6;
  const int lane = tid & 63;
  const int b    = blockIdx.z;

  int m_t, n_t;
  if constexpr (REMAP == 1) {
    // 80 blocks/batch = 40 n-tiles x 2 m-tiles; same-n pairs differ by 8 in
    // dispatch id -> same XCD L2 (B-panel reuse). Bijective for grid=80.
    const int d = blockIdx.x;
    const int xl = d & 7, r = d >> 3;
    m_t = r & 1;
    n_t = (r >> 1) * 8 + xl;
  } else {
    m_t = blockIdx.x / ntn;
    n_t = blockIdx.x % ntn;
  }
  const int m0 = m_t * 256, n0 = n_t * 128;

  // staging geometry: thread covers row s*64 + tid/8, source chunk (tid%8)^(row&7)
  const int srow = tid >> 3;
  const int gq   = (tid & 7) ^ (srow & 7);
  const bf16* Ab = Ag + (long)b * Astr;
  const bf16* aS = Ab + (long)(m0 + srow) * KDIM + gq * 8;
  const bf16* BbB = (const bf16*)Bg + (long)b * Bstr;
  const bf16* bS = nullptr;
  int bsp0 = 0, bsp1 = 0;
  if constexpr (MODE == MODE_LIN) {
    bS = BbB + (long)(n0 + srow) * KDIM + gq * 8;
  } else { // MODE_CONV
    const int na = n0 + srow, nb = na + 64;
    bsp0 = (na / WW) * WPAD + (na % WW);
    bsp1 = (nb / WW) * WPAD + (nb % WW);
  }

  auto STAGE_A = [&](int k0, int buf, int s) {
    gll16(aS + (long)s * (64 * KDIM) + k0, As + buf * 16384 + s * 4096 + tid * 8);
  };
  auto STAGE_B = [&](int k0, int buf, int s) {
    if constexpr (MODE == MODE_LIN) {
      gll16(bS + (long)s * (64 * KDIM) + k0, Bs + buf * 8192 + s * 4096 + tid * 8);
    } else {
      const int tap = k0 >> 9, within = k0 & 511;
      const int kh = tap / 3, kw = tap - kh * 3;
      const int off = kh * WPAD + kw;
      const int sp = (s == 0) ? bsp0 : bsp1;
      gll16(BbB + (long)(sp + off) * CH + within + gq * 8,
            Bs + buf * 8192 + s * 4096 + tid * 8);
    }
  };

  // fragment-read geometry (swizzled)
  const int l15 = lane & 15, l7 = lane & 7, q0 = lane >> 4;
  const int wm = wave >> 2, wn = wave & 3;
  const int aoff = (wm * 128 + l15) * 64;
  const int boff = (wn * 32 + l15) * 64;
  const int c0 = ((q0)     ^ l7) * 8;   // kk=0 chunk
  const int c1 = ((q0 + 4) ^ l7) * 8;   // kk=1 chunk

  f32x4 acc[8][2] = {};

  // prologue: stage tiles 0,1; wait tile 0 (6 newest = tile 1 stay in flight)
  #pragma unroll
  for (int s = 0; s < 4; ++s) STAGE_A(0, 0, s);
  STAGE_B(0, 0, 0); STAGE_B(0, 0, 1);
  #pragma unroll
  for (int s = 0; s < 4; ++s) STAGE_A(64, 1, s);
  STAGE_B(64, 1, 0); STAGE_B(64, 1, 1);
  asm volatile("s_waitcnt vmcnt(6)" ::: "memory");
  __builtin_amdgcn_sched_barrier(0);
  __builtin_amdgcn_s_barrier();
  __builtin_amdgcn_sched_barrier(0);

  for (int t = 0; t < NT; ++t) {
    const int cur = t % 3;
    const int nxt = (t + 2) % 3;
    const int ks  = (t + 2) * 64;
    const bool sg = (t + 2) < NT;
    const bf16* Ac = As + cur * 16384 + aoff;
    const bf16* Bc = Bs + cur * 8192 + boff;

    // phase 0: A-half0 (i=0..3) x all B
    bf16x8 a0[4][2], bf_[2][2];
    #pragma unroll
    for (int i = 0; i < 4; ++i) {
      a0[i][0] = *(const bf16x8*)(Ac + i * 1024 + c0);
      a0[i][1] = *(const bf16x8*)(Ac + i * 1024 + c1);
    }
    #pragma unroll
    for (int j = 0; j < 2; ++j) {
      bf_[j][0] = *(const bf16x8*)(Bc + j * 1024 + c0);
      bf_[j][1] = *(const bf16x8*)(Bc + j * 1024 + c1);
    }
    if (sg) { STAGE_A(ks, nxt, 0); STAGE_A(ks, nxt, 1); STAGE_A(ks, nxt, 2); }
    __builtin_amdgcn_s_setprio(1);
    #pragma unroll
    for (int i = 0; i < 4; ++i)
      #pragma unroll
      for (int j = 0; j < 2; ++j) {
        acc[i][j] = __builtin_amdgcn_mfma_f32_16x16x32_bf16(a0[i][0], bf_[j][0], acc[i][j], 0, 0, 0);
        acc[i][j] = __builtin_amdgcn_mfma_f32_16x16x32_bf16(a0[i][1], bf_[j][1], acc[i][j], 0, 0, 0);
      }
    __builtin_amdgcn_s_setprio(0);

    // phase 1: A-half1 (i=4..7), B frags reused in registers
    bf16x8 a1[4][2];
    #pragma unroll
    for (int i = 0; i < 4; ++i) {
      a1[i][0] = *(const bf16x8*)(Ac + (i + 4) * 1024 + c0);
      a1[i][1] = *(const bf16x8*)(Ac + (i + 4) * 1024 + c1);
    }
    if (sg) { STAGE_A(ks, nxt, 3); STAGE_B(ks, nxt, 0); STAGE_B(ks, nxt, 1); }
    __builtin_amdgcn_s_setprio(1);
    #pragma unroll
    for (int i = 0; i < 4; ++i)
      #pragma unroll
      for (int j = 0; j < 2; ++j) {
        acc[i + 4][j] = __builtin_amdgcn_mfma_f32_16x16x32_bf16(a1[i][0], bf_[j][0], acc[i + 4][j], 0, 0, 0);
        acc[i + 4][j] = __builtin_amdgcn_mfma_f32_16x16x32_bf16(a1[i][1], bf_[j][1], acc[i + 4][j], 0, 0, 0);
      }
    __builtin_amdgcn_s_setprio(0);

    if (t + 1 < NT) {
      if (sg) { asm volatile("s_waitcnt vmcnt(6)" ::: "memory"); }
      else    { asm volatile("s_waitcnt vmcnt(0)" ::: "memory"); }
      __builtin_amdgcn_sched_barrier(0);
      __builtin_amdgcn_s_barrier();
      __builtin_amdgcn_sched_barrier(0);
    }
  }

  const int row0 = m0 + wm * 128 + (lane >> 4) * 4;  // M (+i*16+r)
  const int col0 = n0 + wn * 32 + l15;               // N (+j*16)
  const long zo  = (long)b * Ostr;

  if constexpr (EPI == EPI_SBF) {
    bf16* op = (bf16*)Og + zo;   // write transposed [n][m] (S symmetric)
    #pragma unroll
    for (int i = 0; i < 8; ++i)
      #pragma unroll
      for (int j = 0; j < 2; ++j) {
        bf16x4 pk;
        #pragma unroll
        for (int r = 0; r < 4; ++r) pk[r] = (bf16)(acc[i][j][r] * 0.0625f);
        *(bf16x4*)(op + (long)(col0 + j * 16) * NSPAT + row0 + i * 16) = pk;
      }
  } else if constexpr (EPI == EPI_V1) {
    bf16* op = (bf16*)Og + zo;   // v1T [n][vc]
    #pragma unroll
    for (int i = 0; i < 8; ++i) {
      const int m = row0 + i * 16;
      #pragma unroll
      for (int j = 0; j < 2; ++j) {
        bf16x4 pk;
        #pragma unroll
        for (int r = 0; r < 4; ++r)
          pk[r] = (bf16)fmaxf(acc[i][j][r] + ep0[m + r], 0.0f);
        *(bf16x4*)(op + (long)(col0 + j * 16) * VCH + m) = pk;
      }
    }
  } else { // EPI_CTX: f32 [m][n]
    float* op = (float*)Og + zo;
    #pragma unroll
    for (int i = 0; i < 8; ++i)
      #pragma unroll
      for (int r = 0; r < 4; ++r) {
        const long base = (long)(row0 + i * 16 + r) * NSPAT;
        #pragma unroll
        for (int j = 0; j < 2; ++j)
          op[base + col0 + j * 16] = acc[i][j][r];
      }
  }
}

// ---------------------------------------------------------------------------
// legacy 128x128 kernel (G1, G4, fallback paths) -- verified in R4
template<int MODE, int EPI, int KDIM, int NY>
__global__ __launch_bounds__(256)
void k_gemm(const bf16* __restrict__ Ag, const void* __restrict__ Bg,
            void* __restrict__ Og, const float* __restrict__ ep0,
            const float* __restrict__ ep1,
            long Astr, long Bstr, long Ostr) {
  __shared__ bf16 As[2 * 128 * 32];
  __shared__ bf16 Bs[2 * 128 * 32];
  const int tid  = threadIdx.x;
  const int wave = tid >> 6;
  const int lane = tid & 63;
  const int b    = blockIdx.z;

  const int d  = blockIdx.x;
  const int xl = d & 7;
  const int y  = (d >> 3) % NY;
  const int xh = d / (8 * NY);
  const int n0 = (xh * 8 + xl) * 128;
  const int m0 = y * 128;

  const int rloc = lane >> 2;
  const int cswz = (lane & 3) ^ ((lane >> 3) & 3);
  const int colo = cswz * 8;
  const int r0   = wave * 32 + rloc;
  const int r1   = r0 + 16;

  const bf16* Ab  = Ag + (long)b * Astr;
  const bf16* ag0 = Ab + (long)(m0 + r0) * KDIM + colo;
  const bf16* ag1 = Ab + (long)(m0 + r1) * KDIM + colo;
  bf16* al0 = As + wave * 1024;
  bf16* al1 = As + wave * 1024 + 512;
  bf16* bl0 = Bs + wave * 1024;
  bf16* bl1 = Bs + wave * 1024 + 512;

  const bf16*  BbB = (const bf16*)Bg + (long)b * Bstr;
  const float* Sg  = (const float*)Bg + (long)b * Bstr;
  const bf16* bg0 = nullptr;
  const bf16* bg1 = nullptr;
  if constexpr (MODE == MODE_LIN) {
    bg0 = BbB + (long)(n0 + r0) * KDIM + colo;
    bg1 = BbB + (long)(n0 + r1) * KDIM + colo;
  } else if constexpr (MODE == MODE_PAD) {
    const int na = n0 + r0, nb = n0 + r1;
    bg0 = BbB + ((long)((na / WW + 1) * WPAD + (na % WW) + 1)) * CH + colo;
    bg1 = BbB + ((long)((nb / WW + 1) * WPAD + (nb % WW) + 1)) * CH + colo;
  }

  auto STAGE = [&](int k0, int buf) {
    const int o = buf << 12;
    gll16(ag0 + k0, al0 + o);
    gll16(ag1 + k0, al1 + o);
    if constexpr (MODE == MODE_LIN || MODE == MODE_PAD) {
      gll16(bg0 + k0, bl0 + o);
      gll16(bg1 + k0, bl1 + o);
    } else { // MODE_SIMF32
      #pragma unroll
      for (int p = 0; p < 4; ++p) {
        const int idx = p * 256 + tid;
        const int rr  = idx >> 3;
        const int cg  = (idx & 7) * 4;
        const float4 f = *(const float4*)(Sg + (long)(n0 + rr) * NSPAT + k0 + cg);
        bf16x4 hq;
        hq[0] = (bf16)f.x; hq[1] = (bf16)f.y; hq[2] = (bf16)f.z; hq[3] = (bf16)f.w;
        const int chunk = cg >> 3;
        const int swc   = (((chunk ^ ((rr >> 1) & 3)) << 3) | (cg & 7));
        *(bf16x4*)(Bs + o + rr * 32 + swc) = hq;
      }
    }
  };

  f32x4 acc[4][4] = {};

  const int wm = wave >> 1, wn = wave & 1;
  const int fr  = lane & 15;
  const int qsw = (((lane >> 4) ^ ((fr >> 1) & 3)) << 3);
  const bf16* ArF = As + (wm * 64 + fr) * 32 + qsw;
  const bf16* BrF = Bs + (wn * 64 + fr) * 32 + qsw;

  STAGE(0, 0);
  __syncthreads();
  int cur = 0;
  for (int k0 = 0; k0 < KDIM; k0 += 32) {
    if (k0 + 32 < KDIM) STAGE(k0 + 32, cur ^ 1);
    const int off = cur << 12;
    bf16x8 af[4], bfv[4];
    #pragma unroll
    for (int i = 0; i < 4; ++i) af[i] = *(const bf16x8*)(ArF + off + i * 512);
    #pragma unroll
    for (int j = 0; j < 4; ++j) bfv[j] = *(const bf16x8*)(BrF + off + j * 512);
    #pragma unroll
    for (int i = 0; i < 4; ++i)
      #pragma unroll
      for (int j = 0; j < 4; ++j)
        acc[i][j] = __builtin_amdgcn_mfma_f32_16x16x32_bf16(af[i], bfv[j], acc[i][j], 0, 0, 0);
    __syncthreads();
    cur ^= 1;
  }

  const int row0 = m0 + wm * 64 + (lane >> 4) * 4;
  const int col0 = n0 + wn * 64 + (lane & 15);
  const long zo  = (long)b * Ostr;

  if constexpr (EPI == EPI_KF) {
    bf16* op = (bf16*)Og + zo;
    #pragma unroll
    for (int i = 0; i < 4; ++i) {
      const int m = row0 + i * 16;
      float sc[4], bi[4];
      #pragma unroll
      for (int r = 0; r < 4; ++r) { sc[r] = ep0[m + r]; bi[r] = ep1[m + r]; }
      #pragma unroll
      for (int j = 0; j < 4; ++j) {
        const int n = col0 + j * 16;
        bf16x4 pk;
        #pragma unroll
        for (int r = 0; r < 4; ++r)
          pk[r] = (bf16)fmaxf(acc[i][j][r] * sc[r] + bi[r], 0.0f);
        *(bf16x4*)(op + (long)n * KCH + m) = pk;
      }
    }
  } else if constexpr (EPI == EPI_SF32) {
    float* op = (float*)Og + zo;
    #pragma unroll
    for (int i = 0; i < 4; ++i)
      #pragma unroll
      for (int j = 0; j < 4; ++j) {
        f32x4 sv = acc[i][j];
        sv[0] *= 0.0625f; sv[1] *= 0.0625f; sv[2] *= 0.0625f; sv[3] *= 0.0625f;
        *(f32x4*)(op + (long)(col0 + j * 16) * NSPAT + row0 + i * 16) = sv;
      }
  } else if constexpr (EPI == EPI_V) {
    bf16* op = (bf16*)Og + zo;   // v[m][n]
    #pragma unroll
    for (int i = 0; i < 4; ++i)
      #pragma unroll
      for (int r = 0; r < 4; ++r) {
        const int m = row0 + i * 16 + r;
        const float bi = ep0[m];
        #pragma unroll
        for (int j = 0; j < 4; ++j)
          op[(long)m * NSPAT + col0 + j * 16] = (bf16)fmaxf(acc[i][j][r] + bi, 0.0f);
      }
  } else { // EPI_CTX f32 [m][n]
    float* op = (float*)Og + zo;
    #pragma unroll
    for (int i = 0; i < 4; ++i)
      #pragma unroll
      for (int r = 0; r < 4; ++r) {
        const long base = (long)(row0 + i * 16 + r) * NSPAT;
        #pragma unroll
        for (int j = 0; j < 4; ++j)
          op[base + col0 + j * 16] = acc[i][j][r];
      }
  }
}

// x [B][C][H][W] f32 -> xpadT [B][NPAD][C] bf16, borders zeroed here.
__global__ __launch_bounds__(256)
void k_xpad(const float* __restrict__ x, bf16* __restrict__ xp) {
  __shared__ float t[64 * 81];
  const int cb  = blockIdx.x;
  const int hp  = blockIdx.y;
  const int b   = blockIdx.z;
  const int tid = threadIdx.x;
  const bool border = (hp == 0) || (hp == HPAD - 1);
  if (!border) {
    const float* xb = x + ((long)b * CH + cb * 64) * NSPAT + (hp - 1) * WW;
    for (int idx = tid; idx < 64 * 80; idx += 256) {
      const int cl = idx / 80;
      const int w  = idx - cl * 80;
      t[cl * 81 + w] = xb[(long)cl * NSPAT + w];
    }
    __syncthreads();
  }
  bf16* op = xp + ((long)b * NPAD + (long)hp * WPAD) * CH + cb * 64;
  for (int idx = tid; idx < WPAD * 64; idx += 256) {
    const int wp = idx >> 6;
    const int cl = idx & 63;
    float v = 0.0f;
    if (!border && wp >= 1 && wp <= WW) v = t[cl * 81 + (wp - 1)];
    op[(long)wp * CH + cl] = (bf16)v;
  }
}

__global__ void k_cvt(const float* __restrict__ in, bf16* __restrict__ out, int n) {
  const int i = blockIdx.x * 256 + threadIdx.x;
  if (i < n) out[i] = (bf16)in[i];
}

__global__ void k_cvt_wv1(const float* __restrict__ in, bf16* __restrict__ out) {
  const int o   = blockIdx.x * 256 + threadIdx.x;
  const int c   = o & 511;
  const int t2  = o >> 9;
  const int tap = t2 % 9;
  const int vc  = t2 / 9;
  out[o] = (bf16)in[((long)vc * 512 + c) * 9 + tap];
}

__global__ void k_bnp(const float* bk, const float* gamma, const float* beta,
                      const float* rmean, const float* rvar,
                      float* s, float* t) {
  const int k = threadIdx.x;
  const float sc = gamma[k] / sqrtf(rvar[k] + BN_EPS);
  s[k] = sc;
  t[k] = (bk[k] - rmean[k]) * sc + beta[k];
}

// read bf16 scores, f32 softmax, write f32 sim (d_out) + bf16 in-place
__global__ __launch_bounds__(256)
void k_softmax_bf(bf16* __restrict__ Sb16, float* __restrict__ Sout) {
  const int tid = threadIdx.x;
  bf16*  p  = Sb16 + (long)blockIdx.x * NSPAT;
  float* po = Sout + (long)blockIdx.x * NSPAT;
  float v[20];
  float mx = -3.0e38f;
  #pragma unroll
  for (int q = 0; q < 5; ++q) {
    const bf16x4 h = *(const bf16x4*)(p + (q * 256 + tid) * 4);
    #pragma unroll
    for (int r = 0; r < 4; ++r) {
      v[q * 4 + r] = (float)h[r];
      mx = fmaxf(mx, v[q * 4 + r]);
    }
  }
  __shared__ float red[4];
  #pragma unroll
  for (int o = 32; o > 0; o >>= 1) mx = fmaxf(mx, __shfl_xor(mx, o));
  if ((tid & 63) == 0) red[tid >> 6] = mx;
  __syncthreads();
  mx = fmaxf(fmaxf(red[0], red[1]), fmaxf(red[2], red[3]));
  float sum = 0.0f;
  #pragma unroll
  for (int e = 0; e < 20; ++e) { v[e] = __expf(v[e] - mx); sum += v[e]; }
  #pragma unroll
  for (int o = 32; o > 0; o >>= 1) sum += __shfl_xor(sum, o);
  __syncthreads();
  if ((tid & 63) == 0) red[tid >> 6] = sum;
  __syncthreads();
  sum = (red[0] + red[1]) + (red[2] + red[3]);
  const float inv = 1.0f / sum;
  #pragma unroll
  for (int q = 0; q < 5; ++q) {
    float4 o4;
    o4.x = v[q * 4 + 0] * inv; o4.y = v[q * 4 + 1] * inv;
    o4.z = v[q * 4 + 2] * inv; o4.w = v[q * 4 + 3] * inv;
    *(float4*)(po + (q * 256 + tid) * 4) = o4;
    bf16x4 hb;
    hb[0] = (bf16)o4.x; hb[1] = (bf16)o4.y; hb[2] = (bf16)o4.z; hb[3] = (bf16)o4.w;
    *(bf16x4*)(p + (q * 256 + tid) * 4) = hb;
  }
}

// fallback: f32 softmax in place
__global__ __launch_bounds__(256)
void k_softmax(float* __restrict__ S) {
  const int tid = threadIdx.x;
  float* p = S + (long)blockIdx.x * NSPAT;
  float4 v[5];
  float mx = -3.0e38f;
  #pragma unroll
  for (int q = 0; q < 5; ++q) {
    v[q] = *(const float4*)(p + (q * 256 + tid) * 4);
    mx = fmaxf(mx, fmaxf(fmaxf(v[q].x, v[q].y), fmaxf(v[q].z, v[q].w)));
  }
  __shared__ float red[4];
  #pragma unroll
  for (int o = 32; o > 0; o >>= 1) mx = fmaxf(mx, __shfl_xor(mx, o));
  if ((tid & 63) == 0) red[tid >> 6] = mx;
  __syncthreads();
  mx = fmaxf(fmaxf(red[0], red[1]), fmaxf(red[2], red[3]));
  float sum = 0.0f;
  #pragma unroll
  for (int q = 0; q < 5; ++q) {
    v[q].x = __expf(v[q].x - mx);
    v[q].y = __expf(v[q].y - mx);
    v[q].z = __expf(v[q].z - mx);
    v[q].w = __expf(v[q].w - mx);
    sum += (v[q].x + v[q].y) + (v[q].z + v[q].w);
  }
  #pragma unroll
  for (int o = 32; o > 0; o >>= 1) sum += __shfl_xor(sum, o);
  __syncthreads();
  if ((tid & 63) == 0) red[tid >> 6] = sum;
  __syncthreads();
  sum = (red[0] + red[1]) + (red[2] + red[3]);
  const float inv = 1.0f / sum;
  #pragma unroll
  for (int q = 0; q < 5; ++q) {
    float4 o4;
    o4.x = v[q].x * inv; o4.y = v[q].y * inv;
    o4.z = v[q].z * inv; o4.w = v[q].w * inv;
    *(float4*)(p + (q * 256 + tid) * 4) = o4;
  }
}

extern "C" void kernel_launch(void* const* d_in, const int* in_sizes, int n_in,
                              void* d_out, int out_size, void* d_ws, size_t ws_size,
                              hipStream_t stream) {
  const float* x     = (const float*)d_in[0];
  const float* wk    = (const float*)d_in[1];
  const float* bk    = (const float*)d_in[2];
  const float* gamma = (const float*)d_in[3];
  const float* beta  = (const float*)d_in[4];
  const float* rmean = (const float*)d_in[5];
  const float* rvar  = (const float*)d_in[6];
  const float* wv1   = (const float*)d_in[7];
  const float* bv1   = (const float*)d_in[8];
  const float* wv2   = (const float*)d_in[9];
  const float* bv2   = (const float*)d_in[10];

  float* ctx = (float*)d_out;                    // [B][VC][N]
  float* Sb  = ctx + (long)BATCH * VCH * NSPAT;  // [B][N][N] f32 sim output

  char* w = (char*)d_ws;
  auto alloc = [&](size_t bytes) {
    char* r = w;
    w += (bytes + 255) & ~(size_t)255;
    return r;
  };
  bf16*  xpadT = (bf16*)alloc((size_t)BATCH * NPAD * CH * 2);
  bf16*  kfT   = (bf16*)alloc((size_t)BATCH * NSPAT * KCH * 2);
  bf16*  v1T   = (bf16*)alloc((size_t)BATCH * NSPAT * VCH * 2);
  bf16*  vB    = (bf16*)alloc((size_t)BATCH * VCH * NSPAT * 2);
  bf16*  wkb   = (bf16*)alloc((size_t)KCH * CH * 2);
  bf16*  wv1b  = (bf16*)alloc((size_t)VCH * CH * 9 * 2);
  bf16*  wv2b  = (bf16*)alloc((size_t)VCH * VCH * 2);
  float* bnS   = (float*)alloc(KCH * 4);
  float* bnT   = (float*)alloc(KCH * 4);
  const size_t used = (size_t)(w - (char*)d_ws);
  if (ws_size < used) return;
  const size_t simbytes = (size_t)BATCH * NSPAT * NSPAT * 2;  // 209.7 MB
  bf16* simb = (ws_size - used >= simbytes) ? (bf16*)alloc(simbytes) : nullptr;

  k_xpad<<<dim3(8, HPAD, BATCH), 256, 0, stream>>>(x, xpadT);
  k_cvt<<<(KCH * CH) / 256, 256, 0, stream>>>(wk, wkb, KCH * CH);
  k_cvt_wv1<<<(VCH * CH * 9) / 256, 256, 0, stream>>>(wv1, wv1b);
  k_cvt<<<(VCH * VCH) / 256, 256, 0, stream>>>(wv2, wv2b, VCH * VCH);
  k_bnp<<<1, KCH, 0, stream>>>(bk, gamma, beta, rmean, rvar, bnS, bnT);

  // G1: kfT[b][n][kc] = relu(bn(wk . x))  (128^2 kernel)
  k_gemm<MODE_PAD, EPI_KF, CH, 2><<<dim3(40 * 2, 1, BATCH), 256, 0, stream>>>(
      wkb, xpadT, kfT, bnS, bnT, 0, (long)NPAD * CH, (long)NSPAT * KCH);
  // G3: v1T[b][n][vc] = relu(conv3x3(x))  (deep-pipelined 256x128)
  k_gemm2<MODE_CONV, EPI_V1, CH * 9, 1><<<dim3(80, 1, BATCH), 512, 0, stream>>>(
      wv1b, xpadT, v1T, bv1, 0, (long)NPAD * CH, (long)NSPAT * VCH, 40);
  // G4: v[b][vc][n] = relu(wv2 . v1)  (128^2 kernel)
  k_gemm<MODE_LIN, EPI_V, VCH, 4><<<dim3(40 * 4, 1, BATCH), 256, 0, stream>>>(
      wv2b, v1T, vB, bv2, nullptr, 0, (long)NSPAT * VCH, (long)VCH * NSPAT);

  if (simb) {
    // G2: bf16 scores -> simb (transposed-symmetric write)
    k_gemm2<MODE_LIN, EPI_SBF, KCH, 0><<<dim3(20 * 40, 1, BATCH), 512, 0, stream>>>(
        kfT, kfT, simb, nullptr, (long)NSPAT * KCH, (long)NSPAT * KCH, (long)NSPAT * NSPAT, 40);
    k_softmax_bf<<<BATCH * NSPAT, 256, 0, stream>>>(simb, Sb);
    // G5: context = v . sim^T  (deep-pipelined)
    k_gemm2<MODE_LIN, EPI_CTX, NSPAT, 1><<<dim3(80, 1, BATCH), 512, 0, stream>>>(
        vB, simb, ctx, nullptr, (long)VCH * NSPAT, (long)NSPAT * NSPAT, (long)VCH * NSPAT, 40);
  } else {
    // fallback: f32 scores -> d_out sim region, in-place softmax, f32-staged G5
    k_gemm<MODE_LIN, EPI_SF32, KCH, 40><<<dim3(40 * 40, 1, BATCH), 256, 0, stream>>>(
        kfT, kfT, Sb, nullptr, nullptr, (long)NSPAT * KCH, (long)NSPAT * KCH, (long)NSPAT * NSPAT);
    k_softmax<<<BATCH * NSPAT, 256, 0, stream>>>(Sb);
    k_gemm<MODE_SIMF32, EPI_CTX, NSPAT, 4><<<dim3(40 * 4, 1, BATCH), 256, 0, stream>>>(
        vB, Sb, ctx, nullptr, nullptr, (long)VCH * NSPAT, (long)NSPAT * NSPAT, (long)VCH * NSPAT);
  }
}

// Round 6
// 656.744 us; speedup vs baseline: 1.3076x; 1.0189x over previous
//
#include <hip/hip_runtime.h>
#include <hip/hip_bf16.h>
#include <stdint.h>

typedef __bf16 bf16;
typedef __bf16 bf16x8 __attribute__((ext_vector_type(8)));
typedef __bf16 bf16x4 __attribute__((ext_vector_type(4)));
typedef float f32x4 __attribute__((ext_vector_type(4)));

static constexpr int BATCH = 4;
static constexpr int CH    = 512;
static constexpr int HH    = 64;
static constexpr int WW    = 80;
static constexpr int NSPAT = HH * WW;       // 5120
static constexpr int KCH   = 256;
static constexpr int VCH   = 512;
static constexpr int HPAD  = HH + 2;        // 66
static constexpr int WPAD  = WW + 2;        // 82
static constexpr int NPAD  = HPAD * WPAD;   // 5412
static constexpr float BN_EPS = 1e-5f;

enum { MODE_LIN = 0, MODE_PAD = 1, MODE_CONV = 2, MODE_SIMF32 = 3 };
enum { EPI_KF = 0, EPI_SBF = 1, EPI_SF32 = 2, EPI_V1 = 3, EPI_V = 4, EPI_CTX = 5 };

__device__ __forceinline__ void gll16(const void* g, void* l) {
  __builtin_amdgcn_global_load_lds((const __attribute__((address_space(1))) void*)g,
                                   (__attribute__((address_space(3))) void*)l,
                                   16, 0, 0);
}

// ---------------------------------------------------------------------------
// k_gemm2: deep-pipelined GEMM. C[M,N] = A[M,K]*B[N,K]^T, bf16 in, f32 acc.
// BM=256, BN=128, BK=32, 512 threads (8 waves, 2M x 4N), per-wave out 128x32.
// LDS: 3-buffer ring, 72 KiB total -> 2 blocks/CU (16 waves/CU, launch_bounds
// (512,4) caps VGPR at 128). Iteration t consumes buf[t%3], stages tile t+2
// into buf[(t+2)%3]; boundary = s_waitcnt vmcnt(3) (t+2's 3 loads/thread stay
// in flight ACROSS the raw s_barrier) -- counted-vmcnt pipeline (T3+T4).
// T2 swizzle: LDS slot (row,c) holds global chunk c^((row>>1)&3); realized by
// pre-swizzled global source (gll16 dest must stay linear) + swizzled ds_read.
// T5 setprio(1) around each 8-MFMA cluster.
template<int MODE, int EPI, int KDIM, int REMAP>
__global__ __launch_bounds__(512, 4)
void k_gemm2(const bf16* __restrict__ Ag, const void* __restrict__ Bg,
             void* __restrict__ Og, const float* __restrict__ ep0,
             long Astr, long Bstr, long Ostr, int ntn) {
  __shared__ bf16 As[3 * 8192];   // 3 x 256x32
  __shared__ bf16 Bs[3 * 4096];   // 3 x 128x32
  constexpr int NT = KDIM / 32;
  const int tid  = threadIdx.x;
  const int wave = tid >> 6;
  const int lane = tid & 63;
  const int b    = blockIdx.z;

  int m_t, n_t;
  if constexpr (REMAP == 1) {
    // 80 blocks/batch: pair (m0,m1) of same n-tile differ by 8 in dispatch id
    // -> same XCD L2 (B-panel reuse). Bijective for grid=80.
    const int d = blockIdx.x;
    const int xl = d & 7, r = d >> 3;
    m_t = r & 1;
    n_t = (r >> 1) * 8 + xl;
  } else {
    m_t = blockIdx.x / ntn;
    n_t = blockIdx.x % ntn;
  }
  const int m0 = m_t * 256, n0 = n_t * 128;

  // staging geometry: thread covers row tid/4 (+128 for A s=1), chunk
  // (tid%4)^((row>>1)&3). Note (row+128) has the same swizzle key.
  const int srow = tid >> 2;
  const int gq   = (tid & 3) ^ ((tid >> 3) & 3);
  const bf16* Ab = Ag + (long)b * Astr;
  const bf16* aS = Ab + (long)(m0 + srow) * KDIM + gq * 8;
  const bf16* BbB = (const bf16*)Bg + (long)b * Bstr;
  const bf16* bS = nullptr;
  int bsp = 0;
  if constexpr (MODE == MODE_LIN) {
    bS = BbB + (long)(n0 + srow) * KDIM + gq * 8;
  } else { // MODE_CONV
    const int nb = n0 + srow;
    bsp = (nb / WW) * WPAD + (nb % WW);
  }

  auto STAGE_A = [&](int k0, int buf, int s) {
    gll16(aS + (long)s * (128 * KDIM) + k0, As + buf * 8192 + s * 4096 + tid * 8);
  };
  auto STAGE_B = [&](int k0, int buf) {
    if constexpr (MODE == MODE_LIN) {
      gll16(bS + k0, Bs + buf * 4096 + tid * 8);
    } else {
      const int tap = k0 >> 9, within = k0 & 511;
      const int kh = tap / 3, kw = tap - kh * 3;
      const int off = kh * WPAD + kw;
      gll16(BbB + (long)(bsp + off) * CH + within + gq * 8, Bs + buf * 4096 + tid * 8);
    }
  };

  // fragment-read geometry (swizzled): lane = fr + 16*q0
  const int fr = lane & 15, q0 = lane >> 4;
  const int wm = wave >> 2, wn = wave & 3;
  const int ksw  = ((q0 ^ ((fr >> 1) & 3))) * 8;
  const int aoff = (wm * 128 + fr) * 32 + ksw;
  const int boff = (wn * 32 + fr) * 32 + ksw;

  f32x4 acc[8][2] = {};

  // prologue: stage tiles 0,1; wait tile 0 (3 newest = tile 1 stay in flight)
  STAGE_A(0, 0, 0); STAGE_A(0, 0, 1); STAGE_B(0, 0);
  STAGE_A(32, 1, 0); STAGE_A(32, 1, 1); STAGE_B(32, 1);
  asm volatile("s_waitcnt vmcnt(3)" ::: "memory");
  __builtin_amdgcn_sched_barrier(0);
  __builtin_amdgcn_s_barrier();
  __builtin_amdgcn_sched_barrier(0);

  for (int t = 0; t < NT; ++t) {
    const int cur = t % 3;
    const int nxt = (t + 2) % 3;
    const int ks  = (t + 2) * 32;
    const bool sg = (t + 2) < NT;
    const bf16* Ac = As + cur * 8192 + aoff;
    const bf16* Bc = Bs + cur * 4096 + boff;

    // phase 0: A rows i=0..3 x both B columns
    bf16x8 a0[4], bf_[2];
    #pragma unroll
    for (int i = 0; i < 4; ++i) a0[i] = *(const bf16x8*)(Ac + i * 512);
    #pragma unroll
    for (int j = 0; j < 2; ++j) bf_[j] = *(const bf16x8*)(Bc + j * 512);
    if (sg) { STAGE_A(ks, nxt, 0); STAGE_A(ks, nxt, 1); }
    __builtin_amdgcn_s_setprio(1);
    #pragma unroll
    for (int i = 0; i < 4; ++i)
      #pragma unroll
      for (int j = 0; j < 2; ++j)
        acc[i][j] = __builtin_amdgcn_mfma_f32_16x16x32_bf16(a0[i], bf_[j], acc[i][j], 0, 0, 0);
    __builtin_amdgcn_s_setprio(0);

    // phase 1: A rows i=4..7, B frags reused in registers
    bf16x8 a1[4];
    #pragma unroll
    for (int i = 0; i < 4; ++i) a1[i] = *(const bf16x8*)(Ac + (i + 4) * 512);
    if (sg) STAGE_B(ks, nxt);
    __builtin_amdgcn_s_setprio(1);
    #pragma unroll
    for (int i = 0; i < 4; ++i)
      #pragma unroll
      for (int j = 0; j < 2; ++j)
        acc[i + 4][j] = __builtin_amdgcn_mfma_f32_16x16x32_bf16(a1[i], bf_[j], acc[i + 4][j], 0, 0, 0);
    __builtin_amdgcn_s_setprio(0);

    if (t + 1 < NT) {
      if (sg) { asm volatile("s_waitcnt vmcnt(3)" ::: "memory"); }
      else    { asm volatile("s_waitcnt vmcnt(0)" ::: "memory"); }
      __builtin_amdgcn_sched_barrier(0);
      __builtin_amdgcn_s_barrier();
      __builtin_amdgcn_sched_barrier(0);
    }
  }

  const int row0 = m0 + wm * 128 + q0 * 4;   // M (+i*16+r)
  const int col0 = n0 + wn * 32 + fr;        // N (+j*16)
  const long zo  = (long)b * Ostr;

  if constexpr (EPI == EPI_SBF) {
    bf16* op = (bf16*)Og + zo;   // write transposed [n][m] (S symmetric)
    #pragma unroll
    for (int i = 0; i < 8; ++i)
      #pragma unroll
      for (int j = 0; j < 2; ++j) {
        bf16x4 pk;
        #pragma unroll
        for (int r = 0; r < 4; ++r) pk[r] = (bf16)(acc[i][j][r] * 0.0625f);
        *(bf16x4*)(op + (long)(col0 + j * 16) * NSPAT + row0 + i * 16) = pk;
      }
  } else if constexpr (EPI == EPI_V1) {
    bf16* op = (bf16*)Og + zo;   // v1T [n][vc]
    #pragma unroll
    for (int i = 0; i < 8; ++i) {
      const int m = row0 + i * 16;
      #pragma unroll
      for (int j = 0; j < 2; ++j) {
        bf16x4 pk;
        #pragma unroll
        for (int r = 0; r < 4; ++r)
          pk[r] = (bf16)fmaxf(acc[i][j][r] + ep0[m + r], 0.0f);
        *(bf16x4*)(op + (long)(col0 + j * 16) * VCH + m) = pk;
      }
    }
  } else if constexpr (EPI == EPI_V) {
    bf16* op = (bf16*)Og + zo;   // v[m][n] row-major
    #pragma unroll
    for (int i = 0; i < 8; ++i)
      #pragma unroll
      for (int r = 0; r < 4; ++r) {
        const int m = row0 + i * 16 + r;
        const float bi = ep0[m];
        #pragma unroll
        for (int j = 0; j < 2; ++j)
          op[(long)m * NSPAT + col0 + j * 16] = (bf16)fmaxf(acc[i][j][r] + bi, 0.0f);
      }
  } else { // EPI_CTX: f32 [m][n]
    float* op = (float*)Og + zo;
    #pragma unroll
    for (int i = 0; i < 8; ++i)
      #pragma unroll
      for (int r = 0; r < 4; ++r) {
        const long base = (long)(row0 + i * 16 + r) * NSPAT;
        #pragma unroll
        for (int j = 0; j < 2; ++j)
          op[base + col0 + j * 16] = acc[i][j][r];
      }
  }
}

// ---------------------------------------------------------------------------
// legacy 128x128 kernel (G1, fallback paths) -- verified in R4
template<int MODE, int EPI, int KDIM, int NY>
__global__ __launch_bounds__(256)
void k_gemm(const bf16* __restrict__ Ag, const void* __restrict__ Bg,
            void* __restrict__ Og, const float* __restrict__ ep0,
            const float* __restrict__ ep1,
            long Astr, long Bstr, long Ostr) {
  __shared__ bf16 As[2 * 128 * 32];
  __shared__ bf16 Bs[2 * 128 * 32];
  const int tid  = threadIdx.x;
  const int wave = tid >> 6;
  const int lane = tid & 63;
  const int b    = blockIdx.z;

  const int d  = blockIdx.x;
  const int xl = d & 7;
  const int y  = (d >> 3) % NY;
  const int xh = d / (8 * NY);
  const int n0 = (xh * 8 + xl) * 128;
  const int m0 = y * 128;

  const int rloc = lane >> 2;
  const int cswz = (lane & 3) ^ ((lane >> 3) & 3);
  const int colo = cswz * 8;
  const int r0   = wave * 32 + rloc;
  const int r1   = r0 + 16;

  const bf16* Ab  = Ag + (long)b * Astr;
  const bf16* ag0 = Ab + (long)(m0 + r0) * KDIM + colo;
  const bf16* ag1 = Ab + (long)(m0 + r1) * KDIM + colo;
  bf16* al0 = As + wave * 1024;
  bf16* al1 = As + wave * 1024 + 512;
  bf16* bl0 = Bs + wave * 1024;
  bf16* bl1 = Bs + wave * 1024 + 512;

  const bf16*  BbB = (const bf16*)Bg + (long)b * Bstr;
  const float* Sg  = (const float*)Bg + (long)b * Bstr;
  const bf16* bg0 = nullptr;
  const bf16* bg1 = nullptr;
  if constexpr (MODE == MODE_LIN) {
    bg0 = BbB + (long)(n0 + r0) * KDIM + colo;
    bg1 = BbB + (long)(n0 + r1) * KDIM + colo;
  } else if constexpr (MODE == MODE_PAD) {
    const int na = n0 + r0, nb = n0 + r1;
    bg0 = BbB + ((long)((na / WW + 1) * WPAD + (na % WW) + 1)) * CH + colo;
    bg1 = BbB + ((long)((nb / WW + 1) * WPAD + (nb % WW) + 1)) * CH + colo;
  }

  auto STAGE = [&](int k0, int buf) {
    const int o = buf << 12;
    gll16(ag0 + k0, al0 + o);
    gll16(ag1 + k0, al1 + o);
    if constexpr (MODE == MODE_LIN || MODE == MODE_PAD) {
      gll16(bg0 + k0, bl0 + o);
      gll16(bg1 + k0, bl1 + o);
    } else { // MODE_SIMF32
      #pragma unroll
      for (int p = 0; p < 4; ++p) {
        const int idx = p * 256 + tid;
        const int rr  = idx >> 3;
        const int cg  = (idx & 7) * 4;
        const float4 f = *(const float4*)(Sg + (long)(n0 + rr) * NSPAT + k0 + cg);
        bf16x4 hq;
        hq[0] = (bf16)f.x; hq[1] = (bf16)f.y; hq[2] = (bf16)f.z; hq[3] = (bf16)f.w;
        const int chunk = cg >> 3;
        const int swc   = (((chunk ^ ((rr >> 1) & 3)) << 3) | (cg & 7));
        *(bf16x4*)(Bs + o + rr * 32 + swc) = hq;
      }
    }
  };

  f32x4 acc[4][4] = {};

  const int wm = wave >> 1, wn = wave & 1;
  const int fr  = lane & 15;
  const int qsw = (((lane >> 4) ^ ((fr >> 1) & 3)) << 3);
  const bf16* ArF = As + (wm * 64 + fr) * 32 + qsw;
  const bf16* BrF = Bs + (wn * 64 + fr) * 32 + qsw;

  STAGE(0, 0);
  __syncthreads();
  int cur = 0;
  for (int k0 = 0; k0 < KDIM; k0 += 32) {
    if (k0 + 32 < KDIM) STAGE(k0 + 32, cur ^ 1);
    const int off = cur << 12;
    bf16x8 af[4], bfv[4];
    #pragma unroll
    for (int i = 0; i < 4; ++i) af[i] = *(const bf16x8*)(ArF + off + i * 512);
    #pragma unroll
    for (int j = 0; j < 4; ++j) bfv[j] = *(const bf16x8*)(BrF + off + j * 512);
    #pragma unroll
    for (int i = 0; i < 4; ++i)
      #pragma unroll
      for (int j = 0; j < 4; ++j)
        acc[i][j] = __builtin_amdgcn_mfma_f32_16x16x32_bf16(af[i], bfv[j], acc[i][j], 0, 0, 0);
    __syncthreads();
    cur ^= 1;
  }

  const int row0 = m0 + wm * 64 + (lane >> 4) * 4;
  const int col0 = n0 + wn * 64 + (lane & 15);
  const long zo  = (long)b * Ostr;

  if constexpr (EPI == EPI_KF) {
    bf16* op = (bf16*)Og + zo;
    #pragma unroll
    for (int i = 0; i < 4; ++i) {
      const int m = row0 + i * 16;
      float sc[4], bi[4];
      #pragma unroll
      for (int r = 0; r < 4; ++r) { sc[r] = ep0[m + r]; bi[r] = ep1[m + r]; }
      #pragma unroll
      for (int j = 0; j < 4; ++j) {
        const int n = col0 + j * 16;
        bf16x4 pk;
        #pragma unroll
        for (int r = 0; r < 4; ++r)
          pk[r] = (bf16)fmaxf(acc[i][j][r] * sc[r] + bi[r], 0.0f);
        *(bf16x4*)(op + (long)n * KCH + m) = pk;
      }
    }
  } else if constexpr (EPI == EPI_SF32) {
    float* op = (float*)Og + zo;
    #pragma unroll
    for (int i = 0; i < 4; ++i)
      #pragma unroll
      for (int j = 0; j < 4; ++j) {
        f32x4 sv = acc[i][j];
        sv[0] *= 0.0625f; sv[1] *= 0.0625f; sv[2] *= 0.0625f; sv[3] *= 0.0625f;
        *(f32x4*)(op + (long)(col0 + j * 16) * NSPAT + row0 + i * 16) = sv;
      }
  } else if constexpr (EPI == EPI_V) {
    bf16* op = (bf16*)Og + zo;   // v[m][n]
    #pragma unroll
    for (int i = 0; i < 4; ++i)
      #pragma unroll
      for (int r = 0; r < 4; ++r) {
        const int m = row0 + i * 16 + r;
        const float bi = ep0[m];
        #pragma unroll
        for (int j = 0; j < 4; ++j)
          op[(long)m * NSPAT + col0 + j * 16] = (bf16)fmaxf(acc[i][j][r] + bi, 0.0f);
      }
  } else { // EPI_CTX f32 [m][n]
    float* op = (float*)Og + zo;
    #pragma unroll
    for (int i = 0; i < 4; ++i)
      #pragma unroll
      for (int r = 0; r < 4; ++r) {
        const long base = (long)(row0 + i * 16 + r) * NSPAT;
        #pragma unroll
        for (int j = 0; j < 4; ++j)
          op[base + col0 + j * 16] = acc[i][j][r];
      }
  }
}

// x [B][C][H][W] f32 -> xpadT [B][NPAD][C] bf16, borders zeroed here.
__global__ __launch_bounds__(256)
void k_xpad(const float* __restrict__ x, bf16* __restrict__ xp) {
  __shared__ float t[64 * 81];
  const int cb  = blockIdx.x;
  const int hp  = blockIdx.y;
  const int b   = blockIdx.z;
  const int tid = threadIdx.x;
  const bool border = (hp == 0) || (hp == HPAD - 1);
  if (!border) {
    const float* xb = x + ((long)b * CH + cb * 64) * NSPAT + (hp - 1) * WW;
    for (int idx = tid; idx < 64 * 80; idx += 256) {
      const int cl = idx / 80;
      const int w  = idx - cl * 80;
      t[cl * 81 + w] = xb[(long)cl * NSPAT + w];
    }
    __syncthreads();
  }
  bf16* op = xp + ((long)b * NPAD + (long)hp * WPAD) * CH + cb * 64;
  for (int idx = tid; idx < WPAD * 64; idx += 256) {
    const int wp = idx >> 6;
    const int cl = idx & 63;
    float v = 0.0f;
    if (!border && wp >= 1 && wp <= WW) v = t[cl * 81 + (wp - 1)];
    op[(long)wp * CH + cl] = (bf16)v;
  }
}

__global__ void k_cvt(const float* __restrict__ in, bf16* __restrict__ out, int n) {
  const int i = blockIdx.x * 256 + threadIdx.x;
  if (i < n) out[i] = (bf16)in[i];
}

__global__ void k_cvt_wv1(const float* __restrict__ in, bf16* __restrict__ out) {
  const int o   = blockIdx.x * 256 + threadIdx.x;
  const int c   = o & 511;
  const int t2  = o >> 9;
  const int tap = t2 % 9;
  const int vc  = t2 / 9;
  out[o] = (bf16)in[((long)vc * 512 + c) * 9 + tap];
}

__global__ void k_bnp(const float* bk, const float* gamma, const float* beta,
                      const float* rmean, const float* rvar,
                      float* s, float* t) {
  const int k = threadIdx.x;
  const float sc = gamma[k] / sqrtf(rvar[k] + BN_EPS);
  s[k] = sc;
  t[k] = (bk[k] - rmean[k]) * sc + beta[k];
}

// read bf16 scores, f32 softmax, write f32 sim (d_out) + bf16 in-place
__global__ __launch_bounds__(256)
void k_softmax_bf(bf16* __restrict__ Sb16, float* __restrict__ Sout) {
  const int tid = threadIdx.x;
  bf16*  p  = Sb16 + (long)blockIdx.x * NSPAT;
  float* po = Sout + (long)blockIdx.x * NSPAT;
  float v[20];
  float mx = -3.0e38f;
  #pragma unroll
  for (int q = 0; q < 5; ++q) {
    const bf16x4 h = *(const bf16x4*)(p + (q * 256 + tid) * 4);
    #pragma unroll
    for (int r = 0; r < 4; ++r) {
      v[q * 4 + r] = (float)h[r];
      mx = fmaxf(mx, v[q * 4 + r]);
    }
  }
  __shared__ float red[4];
  #pragma unroll
  for (int o = 32; o > 0; o >>= 1) mx = fmaxf(mx, __shfl_xor(mx, o));
  if ((tid & 63) == 0) red[tid >> 6] = mx;
  __syncthreads();
  mx = fmaxf(fmaxf(red[0], red[1]), fmaxf(red[2], red[3]));
  float sum = 0.0f;
  #pragma unroll
  for (int e = 0; e < 20; ++e) { v[e] = __expf(v[e] - mx); sum += v[e]; }
  #pragma unroll
  for (int o = 32; o > 0; o >>= 1) sum += __shfl_xor(sum, o);
  __syncthreads();
  if ((tid & 63) == 0) red[tid >> 6] = sum;
  __syncthreads();
  sum = (red[0] + red[1]) + (red[2] + red[3]);
  const float inv = 1.0f / sum;
  #pragma unroll
  for (int q = 0; q < 5; ++q) {
    float4 o4;
    o4.x = v[q * 4 + 0] * inv; o4.y = v[q * 4 + 1] * inv;
    o4.z = v[q * 4 + 2] * inv; o4.w = v[q * 4 + 3] * inv;
    *(float4*)(po + (q * 256 + tid) * 4) = o4;
    bf16x4 hb;
    hb[0] = (bf16)o4.x; hb[1] = (bf16)o4.y; hb[2] = (bf16)o4.z; hb[3] = (bf16)o4.w;
    *(bf16x4*)(p + (q * 256 + tid) * 4) = hb;
  }
}

// fallback: f32 softmax in place
__global__ __launch_bounds__(256)
void k_softmax(float* __restrict__ S) {
  const int tid = threadIdx.x;
  float* p = S + (long)blockIdx.x * NSPAT;
  float4 v[5];
  float mx = -3.0e38f;
  #pragma unroll
  for (int q = 0; q < 5; ++q) {
    v[q] = *(const float4*)(p + (q * 256 + tid) * 4);
    mx = fmaxf(mx, fmaxf(fmaxf(v[q].x, v[q].y), fmaxf(v[q].z, v[q].w)));
  }
  __shared__ float red[4];
  #pragma unroll
  for (int o = 32; o > 0; o >>= 1) mx = fmaxf(mx, __shfl_xor(mx, o));
  if ((tid & 63) == 0) red[tid >> 6] = mx;
  __syncthreads();
  mx = fmaxf(fmaxf(red[0], red[1]), fmaxf(red[2], red[3]));
  float sum = 0.0f;
  #pragma unroll
  for (int q = 0; q < 5; ++q) {
    v[q].x = __expf(v[q].x - mx);
    v[q].y = __expf(v[q].y - mx);
    v[q].z = __expf(v[q].z - mx);
    v[q].w = __expf(v[q].w - mx);
    sum += (v[q].x + v[q].y) + (v[q].z + v[q].w);
  }
  #pragma unroll
  for (int o = 32; o > 0; o >>= 1) sum += __shfl_xor(sum, o);
  __syncthreads();
  if ((tid & 63) == 0) red[tid >> 6] = sum;
  __syncthreads();
  sum = (red[0] + red[1]) + (red[2] + red[3]);
  const float inv = 1.0f / sum;
  #pragma unroll
  for (int q = 0; q < 5; ++q) {
    float4 o4;
    o4.x = v[q].x * inv; o4.y = v[q].y * inv;
    o4.z = v[q].z * inv; o4.w = v[q].w * inv;
    *(float4*)(p + (q * 256 + tid) * 4) = o4;
  }
}

extern "C" void kernel_launch(void* const* d_in, const int* in_sizes, int n_in,
                              void* d_out, int out_size, void* d_ws, size_t ws_size,
                              hipStream_t stream) {
  const float* x     = (const float*)d_in[0];
  const float* wk    = (const float*)d_in[1];
  const float* bk    = (const float*)d_in[2];
  const float* gamma = (const float*)d_in[3];
  const float* beta  = (const float*)d_in[4];
  const float* rmean = (const float*)d_in[5];
  const float* rvar  = (const float*)d_in[6];
  const float* wv1   = (const float*)d_in[7];
  const float* bv1   = (const float*)d_in[8];
  const float* wv2   = (const float*)d_in[9];
  const float* bv2   = (const float*)d_in[10];

  float* ctx = (float*)d_out;                    // [B][VC][N]
  float* Sb  = ctx + (long)BATCH * VCH * NSPAT;  // [B][N][N] f32 sim output

  char* w = (char*)d_ws;
  auto alloc = [&](size_t bytes) {
    char* r = w;
    w += (bytes + 255) & ~(size_t)255;
    return r;
  };
  bf16*  xpadT = (bf16*)alloc((size_t)BATCH * NPAD * CH * 2);
  bf16*  kfT   = (bf16*)alloc((size_t)BATCH * NSPAT * KCH * 2);
  bf16*  v1T   = (bf16*)alloc((size_t)BATCH * NSPAT * VCH * 2);
  bf16*  vB    = (bf16*)alloc((size_t)BATCH * VCH * NSPAT * 2);
  bf16*  wkb   = (bf16*)alloc((size_t)KCH * CH * 2);
  bf16*  wv1b  = (bf16*)alloc((size_t)VCH * CH * 9 * 2);
  bf16*  wv2b  = (bf16*)alloc((size_t)VCH * VCH * 2);
  float* bnS   = (float*)alloc(KCH * 4);
  float* bnT   = (float*)alloc(KCH * 4);
  const size_t used = (size_t)(w - (char*)d_ws);
  if (ws_size < used) return;
  const size_t simbytes = (size_t)BATCH * NSPAT * NSPAT * 2;  // 209.7 MB
  bf16* simb = (ws_size - used >= simbytes) ? (bf16*)alloc(simbytes) : nullptr;

  k_xpad<<<dim3(8, HPAD, BATCH), 256, 0, stream>>>(x, xpadT);
  k_cvt<<<(KCH * CH) / 256, 256, 0, stream>>>(wk, wkb, KCH * CH);
  k_cvt_wv1<<<(VCH * CH * 9) / 256, 256, 0, stream>>>(wv1, wv1b);
  k_cvt<<<(VCH * VCH) / 256, 256, 0, stream>>>(wv2, wv2b, VCH * VCH);
  k_bnp<<<1, KCH, 0, stream>>>(bk, gamma, beta, rmean, rvar, bnS, bnT);

  // G1: kfT[b][n][kc] = relu(bn(wk . x))  (128^2 kernel)
  k_gemm<MODE_PAD, EPI_KF, CH, 2><<<dim3(40 * 2, 1, BATCH), 256, 0, stream>>>(
      wkb, xpadT, kfT, bnS, bnT, 0, (long)NPAD * CH, (long)NSPAT * KCH);
  // G3: v1T[b][n][vc] = relu(conv3x3(x))  (deep 256x128, 2 blocks/CU)
  k_gemm2<MODE_CONV, EPI_V1, CH * 9, 1><<<dim3(80, 1, BATCH), 512, 0, stream>>>(
      wv1b, xpadT, v1T, bv1, 0, (long)NPAD * CH, (long)NSPAT * VCH, 40);
  // G4: v[b][vc][n] = relu(wv2 . v1)  (deep 256x128)
  k_gemm2<MODE_LIN, EPI_V, VCH, 1><<<dim3(80, 1, BATCH), 512, 0, stream>>>(
      wv2b, v1T, vB, bv2, 0, (long)NSPAT * VCH, (long)VCH * NSPAT, 40);

  if (simb) {
    // G2: bf16 scores -> simb (transposed-symmetric write)
    k_gemm2<MODE_LIN, EPI_SBF, KCH, 0><<<dim3(20 * 40, 1, BATCH), 512, 0, stream>>>(
        kfT, kfT, simb, nullptr, (long)NSPAT * KCH, (long)NSPAT * KCH, (long)NSPAT * NSPAT, 40);
    k_softmax_bf<<<BATCH * NSPAT, 256, 0, stream>>>(simb, Sb);
    // G5: context = v . sim^T  (deep 256x128)
    k_gemm2<MODE_LIN, EPI_CTX, NSPAT, 1><<<dim3(80, 1, BATCH), 512, 0, stream>>>(
        vB, simb, ctx, nullptr, (long)VCH * NSPAT, (long)NSPAT * NSPAT, (long)VCH * NSPAT, 40);
  } else {
    // fallback: f32 scores -> d_out sim region, in-place softmax, f32-staged G5
    k_gemm<MODE_LIN, EPI_SF32, KCH, 40><<<dim3(40 * 40, 1, BATCH), 256, 0, stream>>>(
        kfT, kfT, Sb, nullptr, nullptr, (long)NSPAT * KCH, (long)NSPAT * KCH, (long)NSPAT * NSPAT);
    k_softmax<<<BATCH * NSPAT, 256, 0, stream>>>(Sb);
    k_gemm<MODE_SIMF32, EPI_CTX, NSPAT, 4><<<dim3(40 * 4, 1, BATCH), 256, 0, stream>>>(
        vB, Sb, ctx, nullptr, nullptr, (long)VCH * NSPAT, (long)NSPAT * NSPAT, (long)VCH * NSPAT);
  }
}

// Round 7
// 612.440 us; speedup vs baseline: 1.4022x; 1.0723x over previous
//
#include <hip/hip_runtime.h>
#include <hip/hip_bf16.h>
#include <stdint.h>

typedef __bf16 bf16;
typedef __bf16 bf16x8 __attribute__((ext_vector_type(8)));
typedef __bf16 bf16x4 __attribute__((ext_vector_type(4)));
typedef float f32x4 __attribute__((ext_vector_type(4)));

static constexpr int BATCH = 4;
static constexpr int CH    = 512;
static constexpr int HH    = 64;
static constexpr int WW    = 80;
static constexpr int NSPAT = HH * WW;       // 5120
static constexpr int KCH   = 256;
static constexpr int VCH   = 512;
static constexpr int HPAD  = HH + 2;        // 66
static constexpr int WPAD  = WW + 2;        // 82
static constexpr int NPAD  = HPAD * WPAD;   // 5412
static constexpr float BN_EPS = 1e-5f;

enum { MODE_LIN = 0, MODE_PAD = 1, MODE_CONV = 2, MODE_SIMF32 = 3 };
enum { EPI_KF = 0, EPI_SBF = 1, EPI_SF32 = 2, EPI_V1 = 3, EPI_V = 4, EPI_CTX = 5 };

__device__ __forceinline__ void gll16(const void* g, void* l) {
  __builtin_amdgcn_global_load_lds((const __attribute__((address_space(1))) void*)g,
                                   (__attribute__((address_space(3))) void*)l,
                                   16, 0, 0);
}

// ---------------------------------------------------------------------------
// k_gemm2 (v3): deep-pipelined GEMM, asymmetric ring depth.
// C[M,N] = A[M,K]*B[N,K]^T, bf16 in, f32 acc. BM=256, BN=128, BK=32,
// 512 threads (8 waves 2Mx4N), per-wave out 128x32 (16 MFMA/tile).
// LDS: A ring-3 (3x16KB) + B ring-4 (4x8KB) = 80 KiB -> 2 blocks/CU.
// Schedule (iteration t): ph0 reads frags + stages A(t+2); MFMA x8;
//   ph1 reads a1 + stages B(t+3); MFMA x8; boundary wait + s_barrier.
// Issue-age order at boundary t: B(t+1),A(t+1)a,b | B(t+2) | A(t+2)a,b,B(t+3)
//   -> steady-state s_waitcnt vmcnt(4) completes exactly {B,A,A}(t+1);
//   B gets 2+ iterations of latency slack (HBM-cold sim stream in G5).
// Tail: vmcnt(3) when B(t+3) unstaged, vmcnt(0) when A(t+2) unstaged.
// T2 swizzle: LDS slot(row,c) holds global chunk c^((row>>1)&3) via
// pre-swizzled global source (gll16 dest stays linear) + swizzled ds_read.
template<int MODE, int EPI, int KDIM, int REMAP>
__global__ __launch_bounds__(512, 4)
void k_gemm2(const bf16* __restrict__ Ag, const void* __restrict__ Bg,
             void* __restrict__ Og, const float* __restrict__ ep0,
             long Astr, long Bstr, long Ostr, int ntn) {
  __shared__ bf16 As[3 * 8192];   // ring-3 of 256x32
  __shared__ bf16 Bs[4 * 4096];   // ring-4 of 128x32
  constexpr int NT = KDIM / 32;
  static_assert(NT >= 4, "pipeline needs >=4 K-tiles");
  const int tid  = threadIdx.x;
  const int wave = tid >> 6;
  const int lane = tid & 63;
  const int b    = blockIdx.z;

  int m_t, n_t;
  if constexpr (REMAP == 1) {
    // 80 blocks/batch: the (m0,m1) pair of one n-tile lands on one XCD -> the
    // second m-tile reads the B-panel from L2. Bijective for grid=80.
    const int d = blockIdx.x;
    const int xl = d & 7, r = d >> 3;
    m_t = r & 1;
    n_t = (r >> 1) * 8 + xl;
  } else {
    m_t = blockIdx.x / ntn;
    n_t = blockIdx.x % ntn;
  }
  const int m0 = m_t * 256, n0 = n_t * 128;

  // staging: thread covers row tid/4 (+128 for A s=1), swizzled source chunk
  const int srow = tid >> 2;
  const int gq   = (tid & 3) ^ ((tid >> 3) & 3);
  const bf16* Ab = Ag + (long)b * Astr;
  const bf16* aS = Ab + (long)(m0 + srow) * KDIM + gq * 8;
  const bf16* BbB = (const bf16*)Bg + (long)b * Bstr;
  const bf16* bS = nullptr;
  int bsp = 0;
  if constexpr (MODE == MODE_LIN) {
    bS = BbB + (long)(n0 + srow) * KDIM + gq * 8;
  } else { // MODE_CONV
    const int nb = n0 + srow;
    bsp = (nb / WW) * WPAD + (nb % WW);
  }

  auto STAGE_A = [&](int k0, int buf, int s) {
    gll16(aS + (long)s * (128 * KDIM) + k0, As + buf * 8192 + s * 4096 + tid * 8);
  };
  auto STAGE_B = [&](int k0, int buf) {
    if constexpr (MODE == MODE_LIN) {
      gll16(bS + k0, Bs + buf * 4096 + tid * 8);
    } else {
      const int tap = k0 >> 9, within = k0 & 511;
      const int kh = tap / 3, kw = tap - kh * 3;
      const int off = kh * WPAD + kw;
      gll16(BbB + (long)(bsp + off) * CH + within + gq * 8, Bs + buf * 4096 + tid * 8);
    }
  };

  // fragment-read geometry (swizzled): lane = fr + 16*q0
  const int fr = lane & 15, q0 = lane >> 4;
  const int wm = wave >> 2, wn = wave & 3;
  const int ksw  = ((q0 ^ ((fr >> 1) & 3))) * 8;
  const int aoff = (wm * 128 + fr) * 32 + ksw;
  const int boff = (wn * 32 + fr) * 32 + ksw;

  f32x4 acc[8][2] = {};

  // prologue: A(0),A(1); B(0),B(1),B(2). wait keeps {A1a,A1b,B1,B2}.
  STAGE_A(0, 0, 0); STAGE_A(0, 0, 1); STAGE_B(0, 0);
  STAGE_A(32, 1, 0); STAGE_A(32, 1, 1); STAGE_B(32, 1);
  if (2 < NT) STAGE_B(64, 2);
  asm volatile("s_waitcnt vmcnt(4)" ::: "memory");
  __builtin_amdgcn_sched_barrier(0);
  __builtin_amdgcn_s_barrier();
  __builtin_amdgcn_sched_barrier(0);

  int ca = 0;  // t % 3
  for (int t = 0; t < NT; ++t) {
    const int cb = t & 3;
    const bf16* Ac = As + ca * 8192 + aoff;
    const bf16* Bc = Bs + cb * 4096 + boff;
    const int na = ca + 2 >= 3 ? ca - 1 : ca + 2;   // (t+2)%3
    const int nb = (t + 3) & 3;

    // phase 0: A rows 0..3 x both B cols; stage A(t+2)
    bf16x8 a0[4], bf_[2];
    #pragma unroll
    for (int i = 0; i < 4; ++i) a0[i] = *(const bf16x8*)(Ac + i * 512);
    #pragma unroll
    for (int j = 0; j < 2; ++j) bf_[j] = *(const bf16x8*)(Bc + j * 512);
    if (t + 2 < NT) { STAGE_A((t + 2) * 32, na, 0); STAGE_A((t + 2) * 32, na, 1); }
    __builtin_amdgcn_s_setprio(1);
    #pragma unroll
    for (int i = 0; i < 4; ++i)
      #pragma unroll
      for (int j = 0; j < 2; ++j)
        acc[i][j] = __builtin_amdgcn_mfma_f32_16x16x32_bf16(a0[i], bf_[j], acc[i][j], 0, 0, 0);
    __builtin_amdgcn_s_setprio(0);

    // phase 1: A rows 4..7 (B frags reused); stage B(t+3)
    bf16x8 a1[4];
    #pragma unroll
    for (int i = 0; i < 4; ++i) a1[i] = *(const bf16x8*)(Ac + (i + 4) * 512);
    if (t + 3 < NT) STAGE_B((t + 3) * 32, nb);
    __builtin_amdgcn_s_setprio(1);
    #pragma unroll
    for (int i = 0; i < 4; ++i)
      #pragma unroll
      for (int j = 0; j < 2; ++j)
        acc[i + 4][j] = __builtin_amdgcn_mfma_f32_16x16x32_bf16(a1[i], bf_[j], acc[i + 4][j], 0, 0, 0);
    __builtin_amdgcn_s_setprio(0);

    if (t + 1 < NT) {
      if (t + 3 < NT)      { asm volatile("s_waitcnt vmcnt(4)" ::: "memory"); }
      else if (t + 2 < NT) { asm volatile("s_waitcnt vmcnt(3)" ::: "memory"); }
      else                 { asm volatile("s_waitcnt vmcnt(0)" ::: "memory"); }
      __builtin_amdgcn_sched_barrier(0);
      __builtin_amdgcn_s_barrier();
      __builtin_amdgcn_sched_barrier(0);
    }
    ca = (ca + 1 >= 3) ? 0 : ca + 1;
  }

  const int row0 = m0 + wm * 128 + q0 * 4;   // M (+i*16+r)
  const int col0 = n0 + wn * 32 + fr;        // N (+j*16)
  const long zo  = (long)b * Ostr;

  if constexpr (EPI == EPI_SBF) {
    bf16* op = (bf16*)Og + zo;   // write transposed [n][m] (S symmetric)
    #pragma unroll
    for (int i = 0; i < 8; ++i)
      #pragma unroll
      for (int j = 0; j < 2; ++j) {
        bf16x4 pk;
        #pragma unroll
        for (int r = 0; r < 4; ++r) pk[r] = (bf16)(acc[i][j][r] * 0.0625f);
        *(bf16x4*)(op + (long)(col0 + j * 16) * NSPAT + row0 + i * 16) = pk;
      }
  } else if constexpr (EPI == EPI_V1) {
    bf16* op = (bf16*)Og + zo;   // v1T [n][vc]
    #pragma unroll
    for (int i = 0; i < 8; ++i) {
      const int m = row0 + i * 16;
      #pragma unroll
      for (int j = 0; j < 2; ++j) {
        bf16x4 pk;
        #pragma unroll
        for (int r = 0; r < 4; ++r)
          pk[r] = (bf16)fmaxf(acc[i][j][r] + ep0[m + r], 0.0f);
        *(bf16x4*)(op + (long)(col0 + j * 16) * VCH + m) = pk;
      }
    }
  } else if constexpr (EPI == EPI_V) {
    bf16* op = (bf16*)Og + zo;   // v[m][n] row-major
    #pragma unroll
    for (int i = 0; i < 8; ++i)
      #pragma unroll
      for (int r = 0; r < 4; ++r) {
        const int m = row0 + i * 16 + r;
        const float bi = ep0[m];
        #pragma unroll
        for (int j = 0; j < 2; ++j)
          op[(long)m * NSPAT + col0 + j * 16] = (bf16)fmaxf(acc[i][j][r] + bi, 0.0f);
      }
  } else { // EPI_CTX: f32 [m][n]
    float* op = (float*)Og + zo;
    #pragma unroll
    for (int i = 0; i < 8; ++i)
      #pragma unroll
      for (int r = 0; r < 4; ++r) {
        const long base = (long)(row0 + i * 16 + r) * NSPAT;
        #pragma unroll
        for (int j = 0; j < 2; ++j)
          op[base + col0 + j * 16] = acc[i][j][r];
      }
  }
}

// ---------------------------------------------------------------------------
// legacy 128x128 kernel (G1, fallback paths)
template<int MODE, int EPI, int KDIM, int NY>
__global__ __launch_bounds__(256)
void k_gemm(const bf16* __restrict__ Ag, const void* __restrict__ Bg,
            void* __restrict__ Og, const float* __restrict__ ep0,
            const float* __restrict__ ep1,
            long Astr, long Bstr, long Ostr) {
  __shared__ bf16 As[2 * 128 * 32];
  __shared__ bf16 Bs[2 * 128 * 32];
  const int tid  = threadIdx.x;
  const int wave = tid >> 6;
  const int lane = tid & 63;
  const int b    = blockIdx.z;

  const int d  = blockIdx.x;
  const int xl = d & 7;
  const int y  = (d >> 3) % NY;
  const int xh = d / (8 * NY);
  const int n0 = (xh * 8 + xl) * 128;
  const int m0 = y * 128;

  const int rloc = lane >> 2;
  const int cswz = (lane & 3) ^ ((lane >> 3) & 3);
  const int colo = cswz * 8;
  const int r0   = wave * 32 + rloc;
  const int r1   = r0 + 16;

  const bf16* Ab  = Ag + (long)b * Astr;
  const bf16* ag0 = Ab + (long)(m0 + r0) * KDIM + colo;
  const bf16* ag1 = Ab + (long)(m0 + r1) * KDIM + colo;
  bf16* al0 = As + wave * 1024;
  bf16* al1 = As + wave * 1024 + 512;
  bf16* bl0 = Bs + wave * 1024;
  bf16* bl1 = Bs + wave * 1024 + 512;

  const bf16*  BbB = (const bf16*)Bg + (long)b * Bstr;
  const float* Sg  = (const float*)Bg + (long)b * Bstr;
  const bf16* bg0 = nullptr;
  const bf16* bg1 = nullptr;
  if constexpr (MODE == MODE_LIN) {
    bg0 = BbB + (long)(n0 + r0) * KDIM + colo;
    bg1 = BbB + (long)(n0 + r1) * KDIM + colo;
  } else if constexpr (MODE == MODE_PAD) {
    const int na = n0 + r0, nb = n0 + r1;
    bg0 = BbB + ((long)((na / WW + 1) * WPAD + (na % WW) + 1)) * CH + colo;
    bg1 = BbB + ((long)((nb / WW + 1) * WPAD + (nb % WW) + 1)) * CH + colo;
  }

  auto STAGE = [&](int k0, int buf) {
    const int o = buf << 12;
    gll16(ag0 + k0, al0 + o);
    gll16(ag1 + k0, al1 + o);
    if constexpr (MODE == MODE_LIN || MODE == MODE_PAD) {
      gll16(bg0 + k0, bl0 + o);
      gll16(bg1 + k0, bl1 + o);
    } else { // MODE_SIMF32
      #pragma unroll
      for (int p = 0; p < 4; ++p) {
        const int idx = p * 256 + tid;
        const int rr  = idx >> 3;
        const int cg  = (idx & 7) * 4;
        const float4 f = *(const float4*)(Sg + (long)(n0 + rr) * NSPAT + k0 + cg);
        bf16x4 hq;
        hq[0] = (bf16)f.x; hq[1] = (bf16)f.y; hq[2] = (bf16)f.z; hq[3] = (bf16)f.w;
        const int chunk = cg >> 3;
        const int swc   = (((chunk ^ ((rr >> 1) & 3)) << 3) | (cg & 7));
        *(bf16x4*)(Bs + o + rr * 32 + swc) = hq;
      }
    }
  };

  f32x4 acc[4][4] = {};

  const int wm = wave >> 1, wn = wave & 1;
  const int fr  = lane & 15;
  const int qsw = (((lane >> 4) ^ ((fr >> 1) & 3)) << 3);
  const bf16* ArF = As + (wm * 64 + fr) * 32 + qsw;
  const bf16* BrF = Bs + (wn * 64 + fr) * 32 + qsw;

  STAGE(0, 0);
  __syncthreads();
  int cur = 0;
  for (int k0 = 0; k0 < KDIM; k0 += 32) {
    if (k0 + 32 < KDIM) STAGE(k0 + 32, cur ^ 1);
    const int off = cur << 12;
    bf16x8 af[4], bfv[4];
    #pragma unroll
    for (int i = 0; i < 4; ++i) af[i] = *(const bf16x8*)(ArF + off + i * 512);
    #pragma unroll
    for (int j = 0; j < 4; ++j) bfv[j] = *(const bf16x8*)(BrF + off + j * 512);
    #pragma unroll
    for (int i = 0; i < 4; ++i)
      #pragma unroll
      for (int j = 0; j < 4; ++j)
        acc[i][j] = __builtin_amdgcn_mfma_f32_16x16x32_bf16(af[i], bfv[j], acc[i][j], 0, 0, 0);
    __syncthreads();
    cur ^= 1;
  }

  const int row0 = m0 + wm * 64 + (lane >> 4) * 4;
  const int col0 = n0 + wn * 64 + (lane & 15);
  const long zo  = (long)b * Ostr;

  if constexpr (EPI == EPI_KF) {
    bf16* op = (bf16*)Og + zo;
    #pragma unroll
    for (int i = 0; i < 4; ++i) {
      const int m = row0 + i * 16;
      float sc[4], bi[4];
      #pragma unroll
      for (int r = 0; r < 4; ++r) { sc[r] = ep0[m + r]; bi[r] = ep1[m + r]; }
      #pragma unroll
      for (int j = 0; j < 4; ++j) {
        const int n = col0 + j * 16;
        bf16x4 pk;
        #pragma unroll
        for (int r = 0; r < 4; ++r)
          pk[r] = (bf16)fmaxf(acc[i][j][r] * sc[r] + bi[r], 0.0f);
        *(bf16x4*)(op + (long)n * KCH + m) = pk;
      }
    }
  } else if constexpr (EPI == EPI_SF32) {
    float* op = (float*)Og + zo;
    #pragma unroll
    for (int i = 0; i < 4; ++i)
      #pragma unroll
      for (int j = 0; j < 4; ++j) {
        f32x4 sv = acc[i][j];
        sv[0] *= 0.0625f; sv[1] *= 0.0625f; sv[2] *= 0.0625f; sv[3] *= 0.0625f;
        *(f32x4*)(op + (long)(col0 + j * 16) * NSPAT + row0 + i * 16) = sv;
      }
  } else if constexpr (EPI == EPI_V) {
    bf16* op = (bf16*)Og + zo;   // v[m][n]
    #pragma unroll
    for (int i = 0; i < 4; ++i)
      #pragma unroll
      for (int r = 0; r < 4; ++r) {
        const int m = row0 + i * 16 + r;
        const float bi = ep0[m];
        #pragma unroll
        for (int j = 0; j < 4; ++j)
          op[(long)m * NSPAT + col0 + j * 16] = (bf16)fmaxf(acc[i][j][r] + bi, 0.0f);
      }
  } else { // EPI_CTX f32 [m][n]
    float* op = (float*)Og + zo;
    #pragma unroll
    for (int i = 0; i < 4; ++i)
      #pragma unroll
      for (int r = 0; r < 4; ++r) {
        const long base = (long)(row0 + i * 16 + r) * NSPAT;
        #pragma unroll
        for (int j = 0; j < 4; ++j)
          op[base + col0 + j * 16] = acc[i][j][r];
      }
  }
}

// x [B][C][H][W] f32 -> xpadT [B][NPAD][C] bf16, borders zeroed here.
__global__ __launch_bounds__(256)
void k_xpad(const float* __restrict__ x, bf16* __restrict__ xp) {
  __shared__ float t[64 * 81];
  const int cb  = blockIdx.x;
  const int hp  = blockIdx.y;
  const int b   = blockIdx.z;
  const int tid = threadIdx.x;
  const bool border = (hp == 0) || (hp == HPAD - 1);
  if (!border) {
    const float* xb = x + ((long)b * CH + cb * 64) * NSPAT + (hp - 1) * WW;
    for (int idx = tid; idx < 64 * 80; idx += 256) {
      const int cl = idx / 80;
      const int w  = idx - cl * 80;
      t[cl * 81 + w] = xb[(long)cl * NSPAT + w];
    }
    __syncthreads();
  }
  bf16* op = xp + ((long)b * NPAD + (long)hp * WPAD) * CH + cb * 64;
  for (int idx = tid; idx < WPAD * 64; idx += 256) {
    const int wp = idx >> 6;
    const int cl = idx & 63;
    float v = 0.0f;
    if (!border && wp >= 1 && wp <= WW) v = t[cl * 81 + (wp - 1)];
    op[(long)wp * CH + cl] = (bf16)v;
  }
}

__global__ void k_cvt(const float* __restrict__ in, bf16* __restrict__ out, int n) {
  const int i = blockIdx.x * 256 + threadIdx.x;
  if (i < n) out[i] = (bf16)in[i];
}

__global__ void k_cvt_wv1(const float* __restrict__ in, bf16* __restrict__ out) {
  const int o   = blockIdx.x * 256 + threadIdx.x;
  const int c   = o & 511;
  const int t2  = o >> 9;
  const int tap = t2 % 9;
  const int vc  = t2 / 9;
  out[o] = (bf16)in[((long)vc * 512 + c) * 9 + tap];
}

__global__ void k_bnp(const float* bk, const float* gamma, const float* beta,
                      const float* rmean, const float* rvar,
                      float* s, float* t) {
  const int k = threadIdx.x;
  const float sc = gamma[k] / sqrtf(rvar[k] + BN_EPS);
  s[k] = sc;
  t[k] = (bk[k] - rmean[k]) * sc + beta[k];
}

// read bf16 scores (16B loads), f32 softmax, write f32 sim (nontemporal, d_out)
// + bf16 sim in-place
__global__ __launch_bounds__(256)
void k_softmax_bf(bf16* __restrict__ Sb16, float* __restrict__ Sout) {
  const int tid = threadIdx.x;
  bf16*  p  = Sb16 + (long)blockIdx.x * NSPAT;
  float* po = Sout + (long)blockIdx.x * NSPAT;
  float v[20];
  float mx = -3.0e38f;
  // 5120 / 256 = 20 elems/thread: 2x bf16x8 + 1x bf16x4, thread-contiguous
  {
    const bf16x8 h0 = *(const bf16x8*)(p + tid * 8);
    const bf16x8 h1 = *(const bf16x8*)(p + 2048 + tid * 8);
    const bf16x4 h2 = *(const bf16x4*)(p + 4096 + tid * 4);
    #pragma unroll
    for (int r = 0; r < 8; ++r) { v[r]     = (float)h0[r]; }
    #pragma unroll
    for (int r = 0; r < 8; ++r) { v[8 + r] = (float)h1[r]; }
    #pragma unroll
    for (int r = 0; r < 4; ++r) { v[16 + r] = (float)h2[r]; }
    #pragma unroll
    for (int e = 0; e < 20; ++e) mx = fmaxf(mx, v[e]);
  }
  __shared__ float red[4];
  #pragma unroll
  for (int o = 32; o > 0; o >>= 1) mx = fmaxf(mx, __shfl_xor(mx, o));
  if ((tid & 63) == 0) red[tid >> 6] = mx;
  __syncthreads();
  mx = fmaxf(fmaxf(red[0], red[1]), fmaxf(red[2], red[3]));
  float sum = 0.0f;
  #pragma unroll
  for (int e = 0; e < 20; ++e) { v[e] = __expf(v[e] - mx); sum += v[e]; }
  #pragma unroll
  for (int o = 32; o > 0; o >>= 1) sum += __shfl_xor(sum, o);
  __syncthreads();
  if ((tid & 63) == 0) red[tid >> 6] = sum;
  __syncthreads();
  sum = (red[0] + red[1]) + (red[2] + red[3]);
  const float inv = 1.0f / sum;
  #pragma unroll
  for (int e = 0; e < 20; ++e) v[e] *= inv;
  // f32 sim: nontemporal 16B stores (streamed output, never re-read)
  #pragma unroll
  for (int g = 0; g < 2; ++g) {
    #pragma unroll
    for (int h = 0; h < 2; ++h) {
      f32x4 o4;
      o4[0] = v[g * 8 + h * 4 + 0]; o4[1] = v[g * 8 + h * 4 + 1];
      o4[2] = v[g * 8 + h * 4 + 2]; o4[3] = v[g * 8 + h * 4 + 3];
      __builtin_nontemporal_store(o4, (f32x4*)(po + g * 2048 + tid * 8 + h * 4));
    }
  }
  {
    f32x4 o4;
    o4[0] = v[16]; o4[1] = v[17]; o4[2] = v[18]; o4[3] = v[19];
    __builtin_nontemporal_store(o4, (f32x4*)(po + 4096 + tid * 4));
  }
  // bf16 sim in-place: 16B + 8B stores
  {
    bf16x8 h0, h1;
    bf16x4 h2;
    #pragma unroll
    for (int r = 0; r < 8; ++r) { h0[r] = (bf16)v[r]; h1[r] = (bf16)v[8 + r]; }
    #pragma unroll
    for (int r = 0; r < 4; ++r) h2[r] = (bf16)v[16 + r];
    *(bf16x8*)(p + tid * 8) = h0;
    *(bf16x8*)(p + 2048 + tid * 8) = h1;
    *(bf16x4*)(p + 4096 + tid * 4) = h2;
  }
}

// fallback: f32 softmax in place
__global__ __launch_bounds__(256)
void k_softmax(float* __restrict__ S) {
  const int tid = threadIdx.x;
  float* p = S + (long)blockIdx.x * NSPAT;
  float4 v[5];
  float mx = -3.0e38f;
  #pragma unroll
  for (int q = 0; q < 5; ++q) {
    v[q] = *(const float4*)(p + (q * 256 + tid) * 4);
    mx = fmaxf(mx, fmaxf(fmaxf(v[q].x, v[q].y), fmaxf(v[q].z, v[q].w)));
  }
  __shared__ float red[4];
  #pragma unroll
  for (int o = 32; o > 0; o >>= 1) mx = fmaxf(mx, __shfl_xor(mx, o));
  if ((tid & 63) == 0) red[tid >> 6] = mx;
  __syncthreads();
  mx = fmaxf(fmaxf(red[0], red[1]), fmaxf(red[2], red[3]));
  float sum = 0.0f;
  #pragma unroll
  for (int q = 0; q < 5; ++q) {
    v[q].x = __expf(v[q].x - mx);
    v[q].y = __expf(v[q].y - mx);
    v[q].z = __expf(v[q].z - mx);
    v[q].w = __expf(v[q].w - mx);
    sum += (v[q].x + v[q].y) + (v[q].z + v[q].w);
  }
  #pragma unroll
  for (int o = 32; o > 0; o >>= 1) sum += __shfl_xor(sum, o);
  __syncthreads();
  if ((tid & 63) == 0) red[tid >> 6] = sum;
  __syncthreads();
  sum = (red[0] + red[1]) + (red[2] + red[3]);
  const float inv = 1.0f / sum;
  #pragma unroll
  for (int q = 0; q < 5; ++q) {
    float4 o4;
    o4.x = v[q].x * inv; o4.y = v[q].y * inv;
    o4.z = v[q].z * inv; o4.w = v[q].w * inv;
    *(float4*)(p + (q * 256 + tid) * 4) = o4;
  }
}

extern "C" void kernel_launch(void* const* d_in, const int* in_sizes, int n_in,
                              void* d_out, int out_size, void* d_ws, size_t ws_size,
                              hipStream_t stream) {
  const float* x     = (const float*)d_in[0];
  const float* wk    = (const float*)d_in[1];
  const float* bk    = (const float*)d_in[2];
  const float* gamma = (const float*)d_in[3];
  const float* beta  = (const float*)d_in[4];
  const float* rmean = (const float*)d_in[5];
  const float* rvar  = (const float*)d_in[6];
  const float* wv1   = (const float*)d_in[7];
  const float* bv1   = (const float*)d_in[8];
  const float* wv2   = (const float*)d_in[9];
  const float* bv2   = (const float*)d_in[10];

  float* ctx = (float*)d_out;                    // [B][VC][N]
  float* Sb  = ctx + (long)BATCH * VCH * NSPAT;  // [B][N][N] f32 sim output

  char* w = (char*)d_ws;
  auto alloc = [&](size_t bytes) {
    char* r = w;
    w += (bytes + 255) & ~(size_t)255;
    return r;
  };
  bf16*  xpadT = (bf16*)alloc((size_t)BATCH * NPAD * CH * 2);
  bf16*  kfT   = (bf16*)alloc((size_t)BATCH * NSPAT * KCH * 2);
  bf16*  v1T   = (bf16*)alloc((size_t)BATCH * NSPAT * VCH * 2);
  bf16*  vB    = (bf16*)alloc((size_t)BATCH * VCH * NSPAT * 2);
  bf16*  wkb   = (bf16*)alloc((size_t)KCH * CH * 2);
  bf16*  wv1b  = (bf16*)alloc((size_t)VCH * CH * 9 * 2);
  bf16*  wv2b  = (bf16*)alloc((size_t)VCH * VCH * 2);
  float* bnS   = (float*)alloc(KCH * 4);
  float* bnT   = (float*)alloc(KCH * 4);
  const size_t used = (size_t)(w - (char*)d_ws);
  if (ws_size < used) return;
  const size_t simbytes = (size_t)BATCH * NSPAT * NSPAT * 2;  // 209.7 MB
  bf16* simb = (ws_size - used >= simbytes) ? (bf16*)alloc(simbytes) : nullptr;

  k_xpad<<<dim3(8, HPAD, BATCH), 256, 0, stream>>>(x, xpadT);
  k_cvt<<<(KCH * CH) / 256, 256, 0, stream>>>(wk, wkb, KCH * CH);
  k_cvt_wv1<<<(VCH * CH * 9) / 256, 256, 0, stream>>>(wv1, wv1b);
  k_cvt<<<(VCH * VCH) / 256, 256, 0, stream>>>(wv2, wv2b, VCH * VCH);
  k_bnp<<<1, KCH, 0, stream>>>(bk, gamma, beta, rmean, rvar, bnS, bnT);

  // G1: kfT[b][n][kc] = relu(bn(wk . x))  (128^2 kernel)
  k_gemm<MODE_PAD, EPI_KF, CH, 2><<<dim3(40 * 2, 1, BATCH), 256, 0, stream>>>(
      wkb, xpadT, kfT, bnS, bnT, 0, (long)NPAD * CH, (long)NSPAT * KCH);
  // G3: v1T[b][n][vc] = relu(conv3x3(x))  (deep 256x128, asym ring)
  k_gemm2<MODE_CONV, EPI_V1, CH * 9, 1><<<dim3(80, 1, BATCH), 512, 0, stream>>>(
      wv1b, xpadT, v1T, bv1, 0, (long)NPAD * CH, (long)NSPAT * VCH, 40);
  // G4: v[b][vc][n] = relu(wv2 . v1)
  k_gemm2<MODE_LIN, EPI_V, VCH, 1><<<dim3(80, 1, BATCH), 512, 0, stream>>>(
      wv2b, v1T, vB, bv2, 0, (long)NSPAT * VCH, (long)VCH * NSPAT, 40);

  if (simb) {
    // G2: bf16 scores -> simb (transposed-symmetric write), 800 blocks/batch
    k_gemm2<MODE_LIN, EPI_SBF, KCH, 0><<<dim3(20 * 40, 1, BATCH), 512, 0, stream>>>(
        kfT, kfT, simb, nullptr, (long)NSPAT * KCH, (long)NSPAT * KCH, (long)NSPAT * NSPAT, 40);
    k_softmax_bf<<<BATCH * NSPAT, 256, 0, stream>>>(simb, Sb);
    // G5: context = v . sim^T  (deep, B=sim gets ring-4 latency slack)
    k_gemm2<MODE_LIN, EPI_CTX, NSPAT, 1><<<dim3(80, 1, BATCH), 512, 0, stream>>>(
        vB, simb, ctx, nullptr, (long)VCH * NSPAT, (long)NSPAT * NSPAT, (long)VCH * NSPAT, 40);
  } else {
    // fallback: f32 scores -> d_out sim region, in-place softmax, f32-staged G5
    k_gemm<MODE_LIN, EPI_SF32, KCH, 40><<<dim3(40 * 40, 1, BATCH), 256, 0, stream>>>(
        kfT, kfT, Sb, nullptr, nullptr, (long)NSPAT * KCH, (long)NSPAT * KCH, (long)NSPAT * NSPAT);
    k_softmax<<<BATCH * NSPAT, 256, 0, stream>>>(Sb);
    k_gemm<MODE_SIMF32, EPI_CTX, NSPAT, 4><<<dim3(40 * 4, 1, BATCH), 256, 0, stream>>>(
        vB, Sb, ctx, nullptr, nullptr, (long)VCH * NSPAT, (long)NSPAT * NSPAT, (long)VCH * NSPAT);
  }
}